// Round 1
// baseline (351.010 us; speedup 1.0000x reference)
//
#include <hip/hip_runtime.h>
#include <hip/hip_bf16.h>
#include <math.h>

typedef __hip_bfloat16 bf16;
typedef __attribute__((ext_vector_type(8))) short short8;
typedef __attribute__((ext_vector_type(4))) float floatx4;

static constexpr int Bn = 2, Sn = 2048, Hn = 16, DHn = 64, DIMn = 1024;
static constexpr int Mn = Bn * Sn;  // 4096 tokens

__device__ __forceinline__ unsigned short bfbits(float f) {
  union { __hip_bfloat16 h; unsigned short u; } cv;
  cv.h = __float2bfloat16(f);
  return cv.u;
}

// ---------------- f32 -> bf16 convert (vectorized, 4/thread) ----------------
__global__ void cvt_kernel(const float* __restrict__ src, unsigned short* __restrict__ dst, int n4) {
  int i = blockIdx.x * blockDim.x + threadIdx.x;
  if (i >= n4) return;
  float4 v = ((const float4*)src)[i];
  ushort4 o;
  o.x = bfbits(v.x); o.y = bfbits(v.y); o.z = bfbits(v.z); o.w = bfbits(v.w);
  ((ushort4*)dst)[i] = o;
}

// ---------------- RoPE cos/sin tables: [S][32] ----------------
__global__ void rope_tab_kernel(float* __restrict__ tc, float* __restrict__ ts) {
  int t = blockIdx.x * 256 + threadIdx.x;  // 2048*32 = 65536
  int pos = t >> 5, i = t & 31;
  float f = powf(10000.0f, -(float)i * (1.0f / 32.0f));
  float a = (float)pos * f;
  tc[t] = cosf(a);
  ts[t] = sinf(a);
}

// ---------------- GEMM: C[m,n] = sum_k A[m,k]*Bw[n,k] + bias[n] ----------------
// M=4096, N=1024, K=1024. 128x128 tile, BK=32, 256 thr (4 waves, 2x2 of 64x64).
// MODE 0: f32 out [M][1024].  MODE 1: bf16 out in V^T layout [B][H][64][S].
template <int MODE>
__global__ __launch_bounds__(256) void gemm_bt_kernel(
    const bf16* __restrict__ A, const bf16* __restrict__ Bw,
    const float* __restrict__ bias, float* __restrict__ Cf,
    unsigned short* __restrict__ Cb) {
  __shared__ bf16 sA[128 * 32];
  __shared__ bf16 sB[128 * 32];
  const int tid = threadIdx.x;
  const int lane = tid & 63, wave = tid >> 6;
  const int wr = wave >> 1, wc = wave & 1;
  const int fr = lane & 15, fq = lane >> 4;
  const int m0 = blockIdx.x * 128, n0 = blockIdx.y * 128;

  floatx4 acc[4][4] = {};

  const int srow = tid >> 2, sch = tid & 3;  // staging: 4 chunks of 8 bf16 per row
  for (int k0 = 0; k0 < 1024; k0 += 32) {
    short8 ra[2], rb[2];
#pragma unroll
    for (int p = 0; p < 2; ++p) {
      int row = p * 64 + srow;
      ra[p] = *(const short8*)(A + (size_t)(m0 + row) * 1024 + k0 + sch * 8);
      rb[p] = *(const short8*)(Bw + (size_t)(n0 + row) * 1024 + k0 + sch * 8);
    }
    __syncthreads();
#pragma unroll
    for (int p = 0; p < 2; ++p) {
      int row = p * 64 + srow;
      *(short8*)(sA + row * 32 + sch * 8) = ra[p];
      *(short8*)(sB + row * 32 + sch * 8) = rb[p];
    }
    __syncthreads();
    short8 af[4], bfr[4];
#pragma unroll
    for (int mi = 0; mi < 4; ++mi)
      af[mi] = *(const short8*)(sA + (wr * 64 + mi * 16 + fr) * 32 + fq * 8);
#pragma unroll
    for (int ni = 0; ni < 4; ++ni)
      bfr[ni] = *(const short8*)(sB + (wc * 64 + ni * 16 + fr) * 32 + fq * 8);
#pragma unroll
    for (int mi = 0; mi < 4; ++mi)
#pragma unroll
      for (int ni = 0; ni < 4; ++ni)
        acc[mi][ni] = __builtin_amdgcn_mfma_f32_16x16x32_bf16(af[mi], bfr[ni], acc[mi][ni], 0, 0, 0);
  }

#pragma unroll
  for (int mi = 0; mi < 4; ++mi)
#pragma unroll
    for (int ni = 0; ni < 4; ++ni)
#pragma unroll
      for (int j = 0; j < 4; ++j) {
        int m = m0 + wr * 64 + mi * 16 + fq * 4 + j;
        int n = n0 + wc * 64 + ni * 16 + fr;
        float v = acc[mi][ni][j] + bias[n];
        if (MODE == 0) {
          Cf[(size_t)m * 1024 + n] = v;
        } else {
          int b = m >> 11, s = m & 2047, h = n >> 6, d = n & 63;
          Cb[(((size_t)b * 16 + h) * 64 + d) * 2048 + s] = bfbits(v);
        }
      }
}

// ---------------- RoPE + l2norm: f32 [B,S,H,64] -> bf16 [B,H,S,64] ----------------
__global__ __launch_bounds__(256) void rope_norm_kernel(
    const float* __restrict__ qf, const float* __restrict__ kf,
    const float* __restrict__ tc, const float* __restrict__ ts,
    unsigned short* __restrict__ qb, unsigned short* __restrict__ kb) {
  int gr = blockIdx.x * 8 + (threadIdx.x >> 5);  // row id over 2*65536
  int j = threadIdx.x & 31;                      // pair index within head dim
  const float* src;
  unsigned short* dst;
  int rr;
  if (gr < Mn * Hn) { src = qf; dst = qb; rr = gr; }
  else { src = kf; dst = kb; rr = gr - Mn * Hn; }
  int h = rr & 15, bs = rr >> 4;
  int s = bs & 2047, b = bs >> 11;
  float2 x = *(const float2*)(src + (size_t)bs * 1024 + h * 64 + 2 * j);
  float c = tc[s * 32 + j], sn = ts[s * 32 + j];
  float y0 = x.x * c - x.y * sn;
  float y1 = x.y * c + x.x * sn;
  float ssq = y0 * y0 + y1 * y1;
#pragma unroll
  for (int msk = 1; msk < 32; msk <<= 1) ssq += __shfl_xor(ssq, msk);
  float inv = rsqrtf(ssq + 1e-6f);
  size_t o = (((size_t)b * 16 + h) * 2048 + s) * 64 + 2 * j;
  ushort2 pk;
  pk.x = bfbits(y0 * inv);
  pk.y = bfbits(y1 * inv);
  *(ushort2*)(dst + o) = pk;
}

// ---------------- causal flash attention ----------------
// grid (32 q-tiles, 32 bh). block 256 = 4 waves x 16 q-rows. KV tile = 64.
__global__ __launch_bounds__(256) void attn_kernel(
    const bf16* __restrict__ qb, const bf16* __restrict__ kb, const bf16* __restrict__ vt,
    const float* __restrict__ ls, unsigned short* __restrict__ out) {
  __shared__ unsigned short p_lds[4][16 * 64];
  const int qt = blockIdx.x, bh = blockIdx.y;
  const int lane = threadIdx.x & 63, wave = threadIdx.x >> 6;
  const int fr = lane & 15, fq = lane >> 4;
  const int q0 = qt * 64;
  const float sc = __expf(ls[0]) * 0.125f;  // exp(logit_scale) * Dh^-0.5

  const size_t qrow = (size_t)bh * 2048 + q0 + wave * 16 + fr;
  short8 qf0 = *(const short8*)(qb + qrow * 64 + fq * 8);
  short8 qf1 = *(const short8*)(qb + qrow * 64 + 32 + fq * 8);

  floatx4 oacc[4] = {};
  float mrun[4], lrun[4];
#pragma unroll
  for (int r = 0; r < 4; ++r) { mrun[r] = -INFINITY; lrun[r] = 0.f; }
  const int rowq = q0 + wave * 16 + fq * 4;  // + r

  for (int t0 = 0; t0 <= q0; t0 += 64) {
    floatx4 sacc[4] = {};
#pragma unroll
    for (int c = 0; c < 4; ++c) {
      const size_t krow = (size_t)bh * 2048 + t0 + c * 16 + fr;
      short8 kf0 = *(const short8*)(kb + krow * 64 + fq * 8);
      short8 kf1 = *(const short8*)(kb + krow * 64 + 32 + fq * 8);
      sacc[c] = __builtin_amdgcn_mfma_f32_16x16x32_bf16(qf0, kf0, sacc[c], 0, 0, 0);
      sacc[c] = __builtin_amdgcn_mfma_f32_16x16x32_bf16(qf1, kf1, sacc[c], 0, 0, 0);
    }
    const bool diag = (t0 == q0);
#pragma unroll
    for (int c = 0; c < 4; ++c)
#pragma unroll
      for (int r = 0; r < 4; ++r) {
        float v = sacc[c][r] * sc;
        if (diag && (t0 + c * 16 + fr) > (rowq + r)) v = -1e30f;
        sacc[c][r] = v;
      }
    float resc[4];
#pragma unroll
    for (int r = 0; r < 4; ++r) {
      float pm = fmaxf(fmaxf(sacc[0][r], sacc[1][r]), fmaxf(sacc[2][r], sacc[3][r]));
#pragma unroll
      for (int msk = 1; msk < 16; msk <<= 1) pm = fmaxf(pm, __shfl_xor(pm, msk));
      float mnew = fmaxf(mrun[r], pm);
      resc[r] = __expf(mrun[r] - mnew);
      mrun[r] = mnew;
    }
    float psum[4] = {0.f, 0.f, 0.f, 0.f};
#pragma unroll
    for (int c = 0; c < 4; ++c)
#pragma unroll
      for (int r = 0; r < 4; ++r) {
        float p = __expf(sacc[c][r] - mrun[r]);
        sacc[c][r] = p;
        psum[r] += p;
      }
#pragma unroll
    for (int r = 0; r < 4; ++r) {
#pragma unroll
      for (int msk = 1; msk < 16; msk <<= 1) psum[r] += __shfl_xor(psum[r], msk);
      lrun[r] = lrun[r] * resc[r] + psum[r];
    }
#pragma unroll
    for (int d = 0; d < 4; ++d)
#pragma unroll
      for (int r = 0; r < 4; ++r) oacc[d][r] *= resc[r];
    // P (acc layout) -> LDS -> A-fragments (wave-private, in-order LDS ops)
#pragma unroll
    for (int c = 0; c < 4; ++c)
#pragma unroll
      for (int r = 0; r < 4; ++r)
        p_lds[wave][(fq * 4 + r) * 64 + c * 16 + fr] = bfbits(sacc[c][r]);
#pragma unroll
    for (int kc = 0; kc < 2; ++kc) {
      short8 pf = *(const short8*)(&p_lds[wave][fr * 64 + kc * 32 + fq * 8]);
#pragma unroll
      for (int d = 0; d < 4; ++d) {
        const size_t vrow = (size_t)bh * 64 + d * 16 + fr;
        short8 vf = *(const short8*)(vt + vrow * 2048 + t0 + kc * 32 + fq * 8);
        oacc[d] = __builtin_amdgcn_mfma_f32_16x16x32_bf16(pf, vf, oacc[d], 0, 0, 0);
      }
    }
  }
  const int b = bh >> 4, h = bh & 15;
#pragma unroll
  for (int d = 0; d < 4; ++d)
#pragma unroll
    for (int r = 0; r < 4; ++r) {
      int s = rowq + r;
      size_t o = ((size_t)b * 2048 + s) * 1024 + h * 64 + d * 16 + fr;
      out[o] = bfbits(oacc[d][r] / lrun[r]);
    }
}

extern "C" void kernel_launch(void* const* d_in, const int* in_sizes, int n_in,
                              void* d_out, int out_size, void* d_ws, size_t ws_size,
                              hipStream_t stream) {
  (void)in_sizes; (void)n_in; (void)out_size; (void)ws_size;
  const float* x  = (const float*)d_in[0];
  const float* Wq = (const float*)d_in[1];
  const float* bq = (const float*)d_in[2];
  const float* Wk = (const float*)d_in[3];
  const float* bk = (const float*)d_in[4];
  const float* Wv = (const float*)d_in[5];
  const float* bv = (const float*)d_in[6];
  const float* Wo = (const float*)d_in[7];
  const float* bo = (const float*)d_in[8];
  const float* lsc = (const float*)d_in[9];
  // d_in[10] = mask: fixed causal triu(k=1), implemented analytically.

  uint8_t* w = (uint8_t*)d_ws;
  const size_t MB = 1ull << 20;
  bf16* xb  = (bf16*)(w + 0);          // 8 MB
  bf16* wqb = (bf16*)(w + 8 * MB);     // 2 MB
  bf16* wkb = (bf16*)(w + 10 * MB);
  bf16* wvb = (bf16*)(w + 12 * MB);
  bf16* wob = (bf16*)(w + 14 * MB);
  float* qf = (float*)(w + 16 * MB);   // 16 MB
  float* kf = (float*)(w + 32 * MB);   // 16 MB
  bf16* qbn = (bf16*)(w + 48 * MB);    // 8 MB  [B,H,S,64]
  bf16* kbn = (bf16*)(w + 56 * MB);    // 8 MB
  bf16* vtb = (bf16*)(w + 64 * MB);    // 8 MB  [B,H,64,S]
  bf16* atb = (bf16*)(w + 72 * MB);    // 8 MB  [B,S,DIM]
  float* tc = (float*)(w + 80 * MB);   // 256 KB
  float* ts = (float*)(w + 80 * MB + 256 * 1024);

  cvt_kernel<<<4096, 256, 0, stream>>>(x, (unsigned short*)xb, Mn * DIMn / 4);
  cvt_kernel<<<1024, 256, 0, stream>>>(Wq, (unsigned short*)wqb, DIMn * DIMn / 4);
  cvt_kernel<<<1024, 256, 0, stream>>>(Wk, (unsigned short*)wkb, DIMn * DIMn / 4);
  cvt_kernel<<<1024, 256, 0, stream>>>(Wv, (unsigned short*)wvb, DIMn * DIMn / 4);
  cvt_kernel<<<1024, 256, 0, stream>>>(Wo, (unsigned short*)wob, DIMn * DIMn / 4);
  rope_tab_kernel<<<256, 256, 0, stream>>>(tc, ts);

  dim3 gg(Mn / 128, DIMn / 128);  // 32 x 8
  gemm_bt_kernel<0><<<gg, 256, 0, stream>>>(xb, wqb, bq, qf, nullptr);
  gemm_bt_kernel<0><<<gg, 256, 0, stream>>>(xb, wkb, bk, kf, nullptr);
  gemm_bt_kernel<1><<<gg, 256, 0, stream>>>(xb, wvb, bv, nullptr, (unsigned short*)vtb);

  rope_norm_kernel<<<Mn * Hn * 2 / 8, 256, 0, stream>>>(qf, kf, tc, ts,
                                                        (unsigned short*)qbn,
                                                        (unsigned short*)kbn);

  attn_kernel<<<dim3(Sn / 64, Bn * Hn), 256, 0, stream>>>(qbn, kbn, vtb, lsc,
                                                          (unsigned short*)atb);

  gemm_bt_kernel<0><<<gg, 256, 0, stream>>>(atb, wob, bo, (float*)d_out, nullptr);
}

// Round 2
// 227.242 us; speedup vs baseline: 1.5447x; 1.5447x over previous
//
#include <hip/hip_runtime.h>
#include <hip/hip_bf16.h>
#include <math.h>

typedef __hip_bfloat16 bf16;
typedef __attribute__((ext_vector_type(8))) short short8;
typedef __attribute__((ext_vector_type(4))) float floatx4;

static constexpr int Bn = 2, Sn = 2048, Hn = 16, DHn = 64, DIMn = 1024;
static constexpr int Mn = Bn * Sn;  // 4096 tokens

__device__ __forceinline__ unsigned short bfbits(float f) {
  union { __hip_bfloat16 h; unsigned short u; } cv;
  cv.h = __float2bfloat16(f);
  return cv.u;
}

// async global->LDS, 16B per lane. dst must be the wave-uniform base;
// HW adds lane*16. src is per-lane.
__device__ __forceinline__ void gload_lds16(const void* g, void* l) {
  __builtin_amdgcn_global_load_lds(
      (const __attribute__((address_space(1))) uint32_t*)g,
      (__attribute__((address_space(3))) uint32_t*)l, 16, 0, 0);
}

// ---------------- f32 -> bf16 convert (vectorized, 4/thread) ----------------
__global__ void cvt_kernel(const float* __restrict__ src, unsigned short* __restrict__ dst, int n4) {
  int i = blockIdx.x * blockDim.x + threadIdx.x;
  if (i >= n4) return;
  float4 v = ((const float4*)src)[i];
  ushort4 o;
  o.x = bfbits(v.x); o.y = bfbits(v.y); o.z = bfbits(v.z); o.w = bfbits(v.w);
  ((ushort4*)dst)[i] = o;
}

// 4 weight matrices (1M elems each) in one launch: grid (1024, 4)
__global__ void cvt4_kernel(const float* __restrict__ a0, const float* __restrict__ a1,
                            const float* __restrict__ a2, const float* __restrict__ a3,
                            unsigned short* __restrict__ o0, unsigned short* __restrict__ o1,
                            unsigned short* __restrict__ o2, unsigned short* __restrict__ o3) {
  const float* s = (blockIdx.y == 0) ? a0 : (blockIdx.y == 1) ? a1 : (blockIdx.y == 2) ? a2 : a3;
  unsigned short* d = (blockIdx.y == 0) ? o0 : (blockIdx.y == 1) ? o1 : (blockIdx.y == 2) ? o2 : o3;
  int i = blockIdx.x * 256 + threadIdx.x;
  float4 v = ((const float4*)s)[i];
  ushort4 o;
  o.x = bfbits(v.x); o.y = bfbits(v.y); o.z = bfbits(v.z); o.w = bfbits(v.w);
  ((ushort4*)d)[i] = o;
}

// ---------------- RoPE cos/sin tables: [S][32] ----------------
__global__ void rope_tab_kernel(float* __restrict__ tc, float* __restrict__ ts) {
  int t = blockIdx.x * 256 + threadIdx.x;  // 2048*32 = 65536
  int pos = t >> 5, i = t & 31;
  float f = powf(10000.0f, -(float)i * (1.0f / 32.0f));
  float a = (float)pos * f;
  tc[t] = cosf(a);
  ts[t] = sinf(a);
}

// ---------------- GEMM: C[m,n] = sum_k A[m,k]*Bw[n,k] + bias[n] ----------------
// m97 structure: 128x128 tile, BK=32, double-buffered LDS, global_load_lds w16.
// MODE 0: f32 out [M][1024].  MODE 1: bf16 out in V^T layout [B][H][64][S].
template <int MODE>
__global__ __launch_bounds__(256) void gemm_bt_kernel(
    const bf16* __restrict__ A, const bf16* __restrict__ Bw,
    const float* __restrict__ bias, float* __restrict__ Cf,
    unsigned short* __restrict__ Cb) {
  __shared__ bf16 sA[2][128 * 32];
  __shared__ bf16 sB[2][128 * 32];
  const int tid = threadIdx.x;
  const int lane = tid & 63, wave = tid >> 6;
  const int wr = wave >> 1, wc = wave & 1;
  const int fr = lane & 15, fq = lane >> 4;
  const int m0 = blockIdx.x * 128, n0 = blockIdx.y * 128;

  floatx4 acc[4][4] = {};

  const int sr = tid >> 2;          // staging row within call (0..63)
  const int sc8 = (tid & 3) * 8;    // staging col (elements)

  auto stage = [&](int buf, int k0) {
#pragma unroll
    for (int call = 0; call < 2; ++call) {
      int row = call * 64 + sr;
      const bf16* ga = A + (size_t)(m0 + row) * 1024 + k0 + sc8;
      const bf16* gb = Bw + (size_t)(n0 + row) * 1024 + k0 + sc8;
      bf16* la = &sA[buf][call * 2048 + wave * 512];
      bf16* lb = &sB[buf][call * 2048 + wave * 512];
      gload_lds16(ga, la);
      gload_lds16(gb, lb);
    }
  };

  stage(0, 0);
  __syncthreads();
  int cur = 0;
  for (int k0 = 0; k0 < 1024; k0 += 32) {
    if (k0 + 32 < 1024) stage(cur ^ 1, k0 + 32);
    short8 af[4], bfr[4];
#pragma unroll
    for (int mi = 0; mi < 4; ++mi)
      af[mi] = *(const short8*)(&sA[cur][(wr * 64 + mi * 16 + fr) * 32 + fq * 8]);
#pragma unroll
    for (int ni = 0; ni < 4; ++ni)
      bfr[ni] = *(const short8*)(&sB[cur][(wc * 64 + ni * 16 + fr) * 32 + fq * 8]);
#pragma unroll
    for (int mi = 0; mi < 4; ++mi)
#pragma unroll
      for (int ni = 0; ni < 4; ++ni)
        acc[mi][ni] = __builtin_amdgcn_mfma_f32_16x16x32_bf16(af[mi], bfr[ni], acc[mi][ni], 0, 0, 0);
    __syncthreads();
    cur ^= 1;
  }

#pragma unroll
  for (int mi = 0; mi < 4; ++mi)
#pragma unroll
    for (int ni = 0; ni < 4; ++ni)
#pragma unroll
      for (int j = 0; j < 4; ++j) {
        int m = m0 + wr * 64 + mi * 16 + fq * 4 + j;
        int n = n0 + wc * 64 + ni * 16 + fr;
        float v = acc[mi][ni][j] + bias[n];
        if (MODE == 0) {
          Cf[(size_t)m * 1024 + n] = v;
        } else {
          int b = m >> 11, s = m & 2047, h = n >> 6, d = n & 63;
          Cb[(((size_t)b * 16 + h) * 64 + d) * 2048 + s] = bfbits(v);
        }
      }
}

// ---------------- RoPE + l2norm: f32 [B,S,H,64] -> bf16 [B,H,S,64] ----------------
__global__ __launch_bounds__(256) void rope_norm_kernel(
    const float* __restrict__ qf, const float* __restrict__ kf,
    const float* __restrict__ tc, const float* __restrict__ ts,
    unsigned short* __restrict__ qb, unsigned short* __restrict__ kb) {
  int gr = blockIdx.x * 8 + (threadIdx.x >> 5);  // row id over 2*65536
  int j = threadIdx.x & 31;                      // pair index within head dim
  const float* src;
  unsigned short* dst;
  int rr;
  if (gr < Mn * Hn) { src = qf; dst = qb; rr = gr; }
  else { src = kf; dst = kb; rr = gr - Mn * Hn; }
  int h = rr & 15, bs = rr >> 4;
  int s = bs & 2047, b = bs >> 11;
  float2 x = *(const float2*)(src + (size_t)bs * 1024 + h * 64 + 2 * j);
  float c = tc[s * 32 + j], sn = ts[s * 32 + j];
  float y0 = x.x * c - x.y * sn;
  float y1 = x.y * c + x.x * sn;
  float ssq = y0 * y0 + y1 * y1;
#pragma unroll
  for (int msk = 1; msk < 32; msk <<= 1) ssq += __shfl_xor(ssq, msk);
  float inv = rsqrtf(ssq + 1e-6f);
  size_t o = (((size_t)b * 16 + h) * 2048 + s) * 64 + 2 * j;
  ushort2 pk;
  pk.x = bfbits(y0 * inv);
  pk.y = bfbits(y1 * inv);
  *(ushort2*)(dst + o) = pk;
}

// ---------------- causal flash attention ----------------
// grid (32 q-tiles, 32 bh). block 256 = 4 waves x 16 q-rows. KV tile = 64.
// K/V double-buffered in LDS via global_load_lds, XOR-swizzled (row&7)<<4.
__global__ __launch_bounds__(256) void attn_kernel(
    const bf16* __restrict__ qb, const bf16* __restrict__ kb, const bf16* __restrict__ vt,
    const float* __restrict__ ls, unsigned short* __restrict__ out) {
  __shared__ bf16 sK[2][64 * 64];
  __shared__ bf16 sV[2][64 * 64];
  __shared__ unsigned short p_lds[4][16 * 64];
  const int qt = (int)gridDim.x - 1 - (int)blockIdx.x;  // heavy tiles first
  const int bh = blockIdx.y;
  const int tid = threadIdx.x;
  const int lane = tid & 63, wave = tid >> 6;
  const int fr = lane & 15, fq = lane >> 4;
  const int q0 = qt * 64;
  const float sc = __expf(ls[0]) * 0.125f;  // exp(logit_scale) * Dh^-0.5

  const size_t qrow = (size_t)bh * 2048 + q0 + wave * 16 + fr;
  short8 qf0 = *(const short8*)(qb + qrow * 64 + fq * 8);
  short8 qf1 = *(const short8*)(qb + qrow * 64 + 32 + fq * 8);

  // staging geometry: LDS tile [64 rows][64 bf16] = 128B rows; 2 calls x 4KB.
  const int str = tid >> 3;            // row within call (0..31)
  const int stb = (tid & 7) * 16;      // byte within row
  const bf16* kgb = kb + (size_t)bh * 2048 * 64;
  const bf16* vgb = vt + (size_t)bh * 64 * 2048;

  auto stage = [&](int buf, int t0) {
#pragma unroll
    for (int call = 0; call < 2; ++call) {
      int row = call * 32 + str;
      int sb = stb ^ ((row & 7) << 4);  // pre-swizzled source byte
      const bf16* gk = kgb + (size_t)(t0 + row) * 64 + sb / 2;
      const bf16* gv = vgb + (size_t)row * 2048 + t0 + sb / 2;
      gload_lds16(gk, &sK[buf][call * 2048 + wave * 512]);
      gload_lds16(gv, &sV[buf][call * 2048 + wave * 512]);
    }
  };

  floatx4 oacc[4] = {};
  float mrun[4], lrun[4];
#pragma unroll
  for (int r = 0; r < 4; ++r) { mrun[r] = -INFINITY; lrun[r] = 0.f; }
  const int rowq = q0 + wave * 16 + fq * 4;  // + r
  const int sw = (fr & 7) << 4;

  stage(0, 0);
  __syncthreads();
  int cur = 0;
  for (int t0 = 0; t0 <= q0; t0 += 64) {
    if (t0 + 64 <= q0) stage(cur ^ 1, t0 + 64);
    const char* sKc = (const char*)sK[cur];
    const char* sVc = (const char*)sV[cur];
    floatx4 sacc[4] = {};
#pragma unroll
    for (int c = 0; c < 4; ++c) {
      int rb = (c * 16 + fr) * 128;
      short8 kf0 = *(const short8*)(sKc + rb + ((fq * 16) ^ sw));
      short8 kf1 = *(const short8*)(sKc + rb + ((64 + fq * 16) ^ sw));
      sacc[c] = __builtin_amdgcn_mfma_f32_16x16x32_bf16(qf0, kf0, sacc[c], 0, 0, 0);
      sacc[c] = __builtin_amdgcn_mfma_f32_16x16x32_bf16(qf1, kf1, sacc[c], 0, 0, 0);
    }
    const bool diag = (t0 == q0);
#pragma unroll
    for (int c = 0; c < 4; ++c)
#pragma unroll
      for (int r = 0; r < 4; ++r) {
        float v = sacc[c][r] * sc;
        if (diag && (t0 + c * 16 + fr) > (rowq + r)) v = -1e30f;
        sacc[c][r] = v;
      }
    float resc[4];
#pragma unroll
    for (int r = 0; r < 4; ++r) {
      float pm = fmaxf(fmaxf(sacc[0][r], sacc[1][r]), fmaxf(sacc[2][r], sacc[3][r]));
#pragma unroll
      for (int msk = 1; msk < 16; msk <<= 1) pm = fmaxf(pm, __shfl_xor(pm, msk));
      float mnew = fmaxf(mrun[r], pm);
      resc[r] = __expf(mrun[r] - mnew);
      mrun[r] = mnew;
    }
    float psum[4] = {0.f, 0.f, 0.f, 0.f};
#pragma unroll
    for (int c = 0; c < 4; ++c)
#pragma unroll
      for (int r = 0; r < 4; ++r) {
        float p = __expf(sacc[c][r] - mrun[r]);
        sacc[c][r] = p;
        psum[r] += p;
      }
#pragma unroll
    for (int r = 0; r < 4; ++r) {
#pragma unroll
      for (int msk = 1; msk < 16; msk <<= 1) psum[r] += __shfl_xor(psum[r], msk);
      lrun[r] = lrun[r] * resc[r] + psum[r];
    }
#pragma unroll
    for (int d = 0; d < 4; ++d)
#pragma unroll
      for (int r = 0; r < 4; ++r) oacc[d][r] *= resc[r];
    // P (acc layout) -> LDS -> A-fragments (wave-private, in-order LDS ops)
#pragma unroll
    for (int c = 0; c < 4; ++c)
#pragma unroll
      for (int r = 0; r < 4; ++r)
        p_lds[wave][(fq * 4 + r) * 64 + c * 16 + fr] = bfbits(sacc[c][r]);
#pragma unroll
    for (int kc = 0; kc < 2; ++kc) {
      short8 pf = *(const short8*)(&p_lds[wave][fr * 64 + kc * 32 + fq * 8]);
#pragma unroll
      for (int d = 0; d < 4; ++d) {
        int rb = (d * 16 + fr) * 128;
        short8 vf = *(const short8*)(sVc + rb + ((kc * 64 + fq * 16) ^ sw));
        oacc[d] = __builtin_amdgcn_mfma_f32_16x16x32_bf16(pf, vf, oacc[d], 0, 0, 0);
      }
    }
    __syncthreads();
    cur ^= 1;
  }
  const int b = bh >> 4, h = bh & 15;
#pragma unroll
  for (int d = 0; d < 4; ++d)
#pragma unroll
    for (int r = 0; r < 4; ++r) {
      int s = rowq + r;
      size_t o = ((size_t)b * 2048 + s) * 1024 + h * 64 + d * 16 + fr;
      out[o] = bfbits(oacc[d][r] / lrun[r]);
    }
}

extern "C" void kernel_launch(void* const* d_in, const int* in_sizes, int n_in,
                              void* d_out, int out_size, void* d_ws, size_t ws_size,
                              hipStream_t stream) {
  (void)in_sizes; (void)n_in; (void)out_size; (void)ws_size;
  const float* x  = (const float*)d_in[0];
  const float* Wq = (const float*)d_in[1];
  const float* bq = (const float*)d_in[2];
  const float* Wk = (const float*)d_in[3];
  const float* bk = (const float*)d_in[4];
  const float* Wv = (const float*)d_in[5];
  const float* bv = (const float*)d_in[6];
  const float* Wo = (const float*)d_in[7];
  const float* bo = (const float*)d_in[8];
  const float* lsc = (const float*)d_in[9];
  // d_in[10] = mask: fixed causal triu(k=1), implemented analytically.

  uint8_t* w = (uint8_t*)d_ws;
  const size_t MB = 1ull << 20;
  bf16* xb  = (bf16*)(w + 0);          // 8 MB
  bf16* wqb = (bf16*)(w + 8 * MB);     // 2 MB
  bf16* wkb = (bf16*)(w + 10 * MB);
  bf16* wvb = (bf16*)(w + 12 * MB);
  bf16* wob = (bf16*)(w + 14 * MB);
  float* qf = (float*)(w + 16 * MB);   // 16 MB
  float* kf = (float*)(w + 32 * MB);   // 16 MB
  bf16* qbn = (bf16*)(w + 48 * MB);    // 8 MB  [B,H,S,64]
  bf16* kbn = (bf16*)(w + 56 * MB);    // 8 MB
  bf16* vtb = (bf16*)(w + 64 * MB);    // 8 MB  [B,H,64,S]
  bf16* atb = (bf16*)(w + 72 * MB);    // 8 MB  [B,S,DIM]
  float* tc = (float*)(w + 80 * MB);   // 256 KB
  float* ts = (float*)(w + 80 * MB + 256 * 1024);

  cvt_kernel<<<4096, 256, 0, stream>>>(x, (unsigned short*)xb, Mn * DIMn / 4);
  cvt4_kernel<<<dim3(1024, 4), 256, 0, stream>>>(
      Wq, Wk, Wv, Wo, (unsigned short*)wqb, (unsigned short*)wkb,
      (unsigned short*)wvb, (unsigned short*)wob);
  rope_tab_kernel<<<256, 256, 0, stream>>>(tc, ts);

  dim3 gg(Mn / 128, DIMn / 128);  // 32 x 8
  gemm_bt_kernel<0><<<gg, 256, 0, stream>>>(xb, wqb, bq, qf, nullptr);
  gemm_bt_kernel<0><<<gg, 256, 0, stream>>>(xb, wkb, bk, kf, nullptr);
  gemm_bt_kernel<1><<<gg, 256, 0, stream>>>(xb, wvb, bv, nullptr, (unsigned short*)vtb);

  rope_norm_kernel<<<Mn * Hn * 2 / 8, 256, 0, stream>>>(qf, kf, tc, ts,
                                                        (unsigned short*)qbn,
                                                        (unsigned short*)kbn);

  attn_kernel<<<dim3(Sn / 64, Bn * Hn), 256, 0, stream>>>(qbn, kbn, vtb, lsc,
                                                          (unsigned short*)atb);

  gemm_bt_kernel<0><<<gg, 256, 0, stream>>>(atb, wob, bo, (float*)d_out, nullptr);
}

// Round 3
// 151.328 us; speedup vs baseline: 2.3195x; 1.5016x over previous
//
#include <hip/hip_runtime.h>
#include <hip/hip_bf16.h>
#include <math.h>

typedef __hip_bfloat16 bf16;
typedef __attribute__((ext_vector_type(8))) short short8;
typedef __attribute__((ext_vector_type(4))) float floatx4;

static constexpr int Bn = 2, Sn = 2048, Hn = 16, DHn = 64, DIMn = 1024;
static constexpr int Mn = Bn * Sn;  // 4096 tokens

#if __has_builtin(__builtin_amdgcn_exp2f)
#define EXP2(x) __builtin_amdgcn_exp2f(x)
#else
#define EXP2(x) exp2f(x)
#endif

__device__ __forceinline__ unsigned short bfbits(float f) {
  union { __hip_bfloat16 h; unsigned short u; } cv;
  cv.h = __float2bfloat16(f);
  return cv.u;
}

__device__ __forceinline__ float bf2f(unsigned short u) {
  union { float f; unsigned int u; } cv;
  cv.u = ((unsigned int)u) << 16;
  return cv.f;
}

// async global->LDS, 16B per lane. dst is wave-uniform base; HW adds lane*16.
__device__ __forceinline__ void gload_lds16(const void* g, void* l) {
  __builtin_amdgcn_global_load_lds(
      (const __attribute__((address_space(1))) uint32_t*)g,
      (__attribute__((address_space(3))) uint32_t*)l, 16, 0, 0);
}

// ---------------- f32 -> bf16 convert (vectorized, 4/thread) ----------------
__global__ void cvt_kernel(const float* __restrict__ src, unsigned short* __restrict__ dst, int n4) {
  int i = blockIdx.x * blockDim.x + threadIdx.x;
  if (i >= n4) return;
  float4 v = ((const float4*)src)[i];
  ushort4 o;
  o.x = bfbits(v.x); o.y = bfbits(v.y); o.z = bfbits(v.z); o.w = bfbits(v.w);
  ((ushort4*)dst)[i] = o;
}

// 4 weight matrices (1M elems each) in one launch: grid (1024, 4)
__global__ void cvt4_kernel(const float* __restrict__ a0, const float* __restrict__ a1,
                            const float* __restrict__ a2, const float* __restrict__ a3,
                            unsigned short* __restrict__ o0, unsigned short* __restrict__ o1,
                            unsigned short* __restrict__ o2, unsigned short* __restrict__ o3) {
  const float* s = (blockIdx.y == 0) ? a0 : (blockIdx.y == 1) ? a1 : (blockIdx.y == 2) ? a2 : a3;
  unsigned short* d = (blockIdx.y == 0) ? o0 : (blockIdx.y == 1) ? o1 : (blockIdx.y == 2) ? o2 : o3;
  int i = blockIdx.x * 256 + threadIdx.x;
  float4 v = ((const float4*)s)[i];
  ushort4 o;
  o.x = bfbits(v.x); o.y = bfbits(v.y); o.z = bfbits(v.z); o.w = bfbits(v.w);
  ((ushort4*)d)[i] = o;
}

// ---------------- RoPE cos/sin tables: [S][32] ----------------
__global__ void rope_tab_kernel(float* __restrict__ tc, float* __restrict__ ts) {
  int t = blockIdx.x * 256 + threadIdx.x;  // 2048*32 = 65536
  int pos = t >> 5, i = t & 31;
  float f = powf(10000.0f, -(float)i * (1.0f / 32.0f));
  float a = (float)pos * f;
  tc[t] = cosf(a);
  ts[t] = sinf(a);
}

// ---------------- fused QKV GEMM ----------------
// grid (32, 24): blockIdx.y>>3 selects Q/K/V, (blockIdx.y&7)*128 = n0.
// Q,K: bf16 out [M][1024]. V: bf16 out transposed [B][H][64][S].
__global__ __launch_bounds__(256) void qkv_kernel(
    const bf16* __restrict__ A,
    const bf16* __restrict__ Wq, const bf16* __restrict__ Wk, const bf16* __restrict__ Wv,
    const float* __restrict__ bq, const float* __restrict__ bk, const float* __restrict__ bv,
    unsigned short* __restrict__ qo, unsigned short* __restrict__ ko,
    unsigned short* __restrict__ vt) {
  __shared__ bf16 sA[2][128 * 32];
  __shared__ bf16 sB[2][128 * 32];
  const int sel = blockIdx.y >> 3;
  const bf16* Bw = (sel == 0) ? Wq : (sel == 1) ? Wk : Wv;
  const float* bias = (sel == 0) ? bq : (sel == 1) ? bk : bv;
  const int tid = threadIdx.x;
  const int lane = tid & 63, wave = tid >> 6;
  const int wr = wave >> 1, wc = wave & 1;
  const int fr = lane & 15, fq = lane >> 4;
  const int m0 = blockIdx.x * 128, n0 = (blockIdx.y & 7) * 128;

  floatx4 acc[4][4] = {};
  const int sr = tid >> 2;
  const int sc8 = (tid & 3) * 8;

  auto stage = [&](int buf, int k0) {
#pragma unroll
    for (int call = 0; call < 2; ++call) {
      int row = call * 64 + sr;
      const bf16* ga = A + (size_t)(m0 + row) * 1024 + k0 + sc8;
      const bf16* gb = Bw + (size_t)(n0 + row) * 1024 + k0 + sc8;
      gload_lds16(ga, &sA[buf][call * 2048 + wave * 512]);
      gload_lds16(gb, &sB[buf][call * 2048 + wave * 512]);
    }
  };

  stage(0, 0);
  __syncthreads();
  int cur = 0;
  for (int k0 = 0; k0 < 1024; k0 += 32) {
    if (k0 + 32 < 1024) stage(cur ^ 1, k0 + 32);
    short8 af[4], bfr[4];
#pragma unroll
    for (int mi = 0; mi < 4; ++mi)
      af[mi] = *(const short8*)(&sA[cur][(wr * 64 + mi * 16 + fr) * 32 + fq * 8]);
#pragma unroll
    for (int ni = 0; ni < 4; ++ni)
      bfr[ni] = *(const short8*)(&sB[cur][(wc * 64 + ni * 16 + fr) * 32 + fq * 8]);
#pragma unroll
    for (int mi = 0; mi < 4; ++mi)
#pragma unroll
      for (int ni = 0; ni < 4; ++ni)
        acc[mi][ni] = __builtin_amdgcn_mfma_f32_16x16x32_bf16(af[mi], bfr[ni], acc[mi][ni], 0, 0, 0);
    __syncthreads();
    cur ^= 1;
  }

  unsigned short* dst = (sel == 0) ? qo : ko;
#pragma unroll
  for (int mi = 0; mi < 4; ++mi)
#pragma unroll
    for (int ni = 0; ni < 4; ++ni)
#pragma unroll
      for (int j = 0; j < 4; ++j) {
        int m = m0 + wr * 64 + mi * 16 + fq * 4 + j;
        int n = n0 + wc * 64 + ni * 16 + fr;
        float v = acc[mi][ni][j] + bias[n];
        if (sel < 2) {
          dst[(size_t)m * 1024 + n] = bfbits(v);
        } else {
          int b = m >> 11, s = m & 2047, h = n >> 6, d = n & 63;
          vt[(((size_t)b * 16 + h) * 64 + d) * 2048 + s] = bfbits(v);
        }
      }
}

// ---------------- Wo GEMM: f32 out ----------------
__global__ __launch_bounds__(256) void gemm_bt_kernel(
    const bf16* __restrict__ A, const bf16* __restrict__ Bw,
    const float* __restrict__ bias, float* __restrict__ Cf) {
  __shared__ bf16 sA[2][128 * 32];
  __shared__ bf16 sB[2][128 * 32];
  const int tid = threadIdx.x;
  const int lane = tid & 63, wave = tid >> 6;
  const int wr = wave >> 1, wc = wave & 1;
  const int fr = lane & 15, fq = lane >> 4;
  const int m0 = blockIdx.x * 128, n0 = blockIdx.y * 128;

  floatx4 acc[4][4] = {};
  const int sr = tid >> 2;
  const int sc8 = (tid & 3) * 8;

  auto stage = [&](int buf, int k0) {
#pragma unroll
    for (int call = 0; call < 2; ++call) {
      int row = call * 64 + sr;
      gload_lds16(A + (size_t)(m0 + row) * 1024 + k0 + sc8, &sA[buf][call * 2048 + wave * 512]);
      gload_lds16(Bw + (size_t)(n0 + row) * 1024 + k0 + sc8, &sB[buf][call * 2048 + wave * 512]);
    }
  };

  stage(0, 0);
  __syncthreads();
  int cur = 0;
  for (int k0 = 0; k0 < 1024; k0 += 32) {
    if (k0 + 32 < 1024) stage(cur ^ 1, k0 + 32);
    short8 af[4], bfr[4];
#pragma unroll
    for (int mi = 0; mi < 4; ++mi)
      af[mi] = *(const short8*)(&sA[cur][(wr * 64 + mi * 16 + fr) * 32 + fq * 8]);
#pragma unroll
    for (int ni = 0; ni < 4; ++ni)
      bfr[ni] = *(const short8*)(&sB[cur][(wc * 64 + ni * 16 + fr) * 32 + fq * 8]);
#pragma unroll
    for (int mi = 0; mi < 4; ++mi)
#pragma unroll
      for (int ni = 0; ni < 4; ++ni)
        acc[mi][ni] = __builtin_amdgcn_mfma_f32_16x16x32_bf16(af[mi], bfr[ni], acc[mi][ni], 0, 0, 0);
    __syncthreads();
    cur ^= 1;
  }

#pragma unroll
  for (int mi = 0; mi < 4; ++mi)
#pragma unroll
    for (int ni = 0; ni < 4; ++ni)
#pragma unroll
      for (int j = 0; j < 4; ++j) {
        int m = m0 + wr * 64 + mi * 16 + fq * 4 + j;
        int n = n0 + wc * 64 + ni * 16 + fr;
        Cf[(size_t)m * 1024 + n] = acc[mi][ni][j] + bias[n];
      }
}

// ---------------- RoPE + l2norm: bf16 [B,S,H,64] -> bf16 [B,H,S,64] ----------------
__global__ __launch_bounds__(256) void rope_norm_kernel(
    const unsigned short* __restrict__ qf, const unsigned short* __restrict__ kf,
    const float* __restrict__ tc, const float* __restrict__ ts,
    unsigned short* __restrict__ qb, unsigned short* __restrict__ kb) {
  int gr = blockIdx.x * 8 + (threadIdx.x >> 5);  // row id over 2*65536
  int j = threadIdx.x & 31;                      // pair index within head dim
  const unsigned short* src;
  unsigned short* dst;
  int rr;
  if (gr < Mn * Hn) { src = qf; dst = qb; rr = gr; }
  else { src = kf; dst = kb; rr = gr - Mn * Hn; }
  int h = rr & 15, bs = rr >> 4;
  int s = bs & 2047, b = bs >> 11;
  ushort2 xr = *(const ushort2*)(src + (size_t)bs * 1024 + h * 64 + 2 * j);
  float x0 = bf2f(xr.x), x1 = bf2f(xr.y);
  float c = tc[s * 32 + j], sn = ts[s * 32 + j];
  float y0 = x0 * c - x1 * sn;
  float y1 = x1 * c + x0 * sn;
  float ssq = y0 * y0 + y1 * y1;
#pragma unroll
  for (int msk = 1; msk < 32; msk <<= 1) ssq += __shfl_xor(ssq, msk);
  float inv = rsqrtf(ssq + 1e-6f);
  size_t o = (((size_t)b * 16 + h) * 2048 + s) * 64 + 2 * j;
  ushort2 pk;
  pk.x = bfbits(y0 * inv);
  pk.y = bfbits(y1 * inv);
  *(ushort2*)(dst + o) = pk;
}

// ---------------- causal flash attention ----------------
// grid (32 q-tiles, 32 bh). block 256 = 4 waves x 16 q-rows. KV tile = 64.
// K/V double-buffered LDS via global_load_lds, XOR-swizzled ((row&7)<<4).
// Softmax: exp2-domain, scale folded; defer-max (__all ballot, THR=11.5 log2);
// row-sums via ones-MFMA; P packed by truncation into swizzled p_lds.
__global__ __launch_bounds__(256) void attn_kernel(
    const bf16* __restrict__ qb, const bf16* __restrict__ kb, const bf16* __restrict__ vt,
    const float* __restrict__ ls, unsigned short* __restrict__ out) {
  __shared__ bf16 sK[2][64 * 64];
  __shared__ bf16 sV[2][64 * 64];
  __shared__ char p_lds[4][16 * 128];
  const int qt = (int)gridDim.x - 1 - (int)blockIdx.x;  // heavy tiles first
  const int bh = blockIdx.y;
  const int tid = threadIdx.x;
  const int lane = tid & 63, wave = tid >> 6;
  const int fr = lane & 15, fq = lane >> 4;
  const int q0 = qt * 64;
  // scl2 = exp(logit_scale) * Dh^-0.5 * log2(e): scores -> log2 domain
  const float scl2 = __expf(ls[0]) * 0.125f * 1.44269504f;

  const size_t qrow = (size_t)bh * 2048 + q0 + wave * 16 + fr;
  short8 qf0 = *(const short8*)(qb + qrow * 64 + fq * 8);
  short8 qf1 = *(const short8*)(qb + qrow * 64 + 32 + fq * 8);

  const int str = tid >> 3;            // staging row within call (0..31)
  const int stb = (tid & 7) * 16;      // staging byte within row
  const bf16* kgb = kb + (size_t)bh * 2048 * 64;
  const bf16* vgb = vt + (size_t)bh * 64 * 2048;

  auto stage = [&](int buf, int t0) {
#pragma unroll
    for (int call = 0; call < 2; ++call) {
      int row = call * 32 + str;
      int sb = stb ^ ((row & 7) << 4);  // pre-swizzled source byte
      const bf16* gk = kgb + (size_t)(t0 + row) * 64 + sb / 2;
      const bf16* gv = vgb + (size_t)row * 2048 + t0 + sb / 2;
      gload_lds16(gk, &sK[buf][call * 2048 + wave * 512]);
      gload_lds16(gv, &sV[buf][call * 2048 + wave * 512]);
    }
  };

  floatx4 oacc[4] = {};
  float mb2[4], lrun[4];
#pragma unroll
  for (int r = 0; r < 4; ++r) { mb2[r] = -INFINITY; lrun[r] = 0.f; }
  const int rowq = q0 + wave * 16 + fq * 4;  // + r
  const int sw = (fr & 7) << 4;
  char* pw = p_lds[wave];
  short8 onesf;
#pragma unroll
  for (int i = 0; i < 8; ++i) onesf[i] = 0x3F80;  // bf16 1.0

  stage(0, 0);
  __syncthreads();
  int cur = 0;
  for (int t0 = 0; t0 <= q0; t0 += 64) {
    if (t0 + 64 <= q0) stage(cur ^ 1, t0 + 64);
    const char* sKc = (const char*)sK[cur];
    const char* sVc = (const char*)sV[cur];
    floatx4 sacc[4] = {};
#pragma unroll
    for (int c = 0; c < 4; ++c) {
      int rb = (c * 16 + fr) * 128;
      short8 kf0 = *(const short8*)(sKc + rb + ((fq * 16) ^ sw));
      short8 kf1 = *(const short8*)(sKc + rb + ((64 + fq * 16) ^ sw));
      sacc[c] = __builtin_amdgcn_mfma_f32_16x16x32_bf16(qf0, kf0, sacc[c], 0, 0, 0);
      sacc[c] = __builtin_amdgcn_mfma_f32_16x16x32_bf16(qf1, kf1, sacc[c], 0, 0, 0);
    }
    if (t0 == q0) {  // diagonal tile: causal mask (raw-score units)
#pragma unroll
      for (int c = 0; c < 4; ++c)
#pragma unroll
        for (int r = 0; r < 4; ++r)
          if ((t0 + c * 16 + fr) > (rowq + r)) sacc[c][r] = -1e30f;
    }
    // per-lane partial max over this lane's 16 scores
    float pl[4];
#pragma unroll
    for (int r = 0; r < 4; ++r)
      pl[r] = fmaxf(fmaxf(sacc[0][r], sacc[1][r]), fmaxf(sacc[2][r], sacc[3][r]));
    float cmax = -INFINITY;
#pragma unroll
    for (int r = 0; r < 4; ++r) cmax = fmaxf(cmax, pl[r] * scl2 - mb2[r]);
    if (!__all(cmax <= 11.5f)) {  // slow path: full row-max + rescale
#pragma unroll
      for (int r = 0; r < 4; ++r) {
        float pm = pl[r];
#pragma unroll
        for (int msk = 1; msk < 16; msk <<= 1) pm = fmaxf(pm, __shfl_xor(pm, msk));
        float mnew = fmaxf(mb2[r], pm * scl2);
        float rs = EXP2(mb2[r] - mnew);
        mb2[r] = mnew;
        lrun[r] *= rs;
#pragma unroll
        for (int d = 0; d < 4; ++d) oacc[d][r] *= rs;
      }
    }
    // P = exp2(s*scl2 - mb2), truncate-pack to bf16 into swizzled p_lds
#pragma unroll
    for (int c = 0; c < 4; ++c)
#pragma unroll
      for (int r = 0; r < 4; ++r) {
        union { float f; unsigned int u; } pu;
        pu.f = EXP2(sacc[c][r] * scl2 - mb2[r]);
        int prow = fq * 4 + r;
        *(unsigned short*)(pw + prow * 128 + ((c * 32 + 2 * fr) ^ ((prow & 7) << 4))) =
            (unsigned short)(pu.u >> 16);
      }
    short8 pf0 = *(const short8*)(pw + fr * 128 + ((fq * 16) ^ sw));
    short8 pf1 = *(const short8*)(pw + fr * 128 + ((64 + fq * 16) ^ sw));
    floatx4 tsum = {};
    tsum = __builtin_amdgcn_mfma_f32_16x16x32_bf16(pf0, onesf, tsum, 0, 0, 0);
    tsum = __builtin_amdgcn_mfma_f32_16x16x32_bf16(pf1, onesf, tsum, 0, 0, 0);
#pragma unroll
    for (int d = 0; d < 4; ++d) {
      int rb = (d * 16 + fr) * 128;
      short8 vf0 = *(const short8*)(sVc + rb + ((fq * 16) ^ sw));
      short8 vf1 = *(const short8*)(sVc + rb + ((64 + fq * 16) ^ sw));
      oacc[d] = __builtin_amdgcn_mfma_f32_16x16x32_bf16(pf0, vf0, oacc[d], 0, 0, 0);
      oacc[d] = __builtin_amdgcn_mfma_f32_16x16x32_bf16(pf1, vf1, oacc[d], 0, 0, 0);
    }
#pragma unroll
    for (int r = 0; r < 4; ++r) lrun[r] += tsum[r];
    __syncthreads();
    cur ^= 1;
  }
  const int b = bh >> 4, h = bh & 15;
#pragma unroll
  for (int r = 0; r < 4; ++r) {
    float il = 1.0f / lrun[r];
#pragma unroll
    for (int d = 0; d < 4; ++d) {
      int s = rowq + r;
      size_t o = ((size_t)b * 2048 + s) * 1024 + h * 64 + d * 16 + fr;
      out[o] = bfbits(oacc[d][r] * il);
    }
  }
}

extern "C" void kernel_launch(void* const* d_in, const int* in_sizes, int n_in,
                              void* d_out, int out_size, void* d_ws, size_t ws_size,
                              hipStream_t stream) {
  (void)in_sizes; (void)n_in; (void)out_size; (void)ws_size;
  const float* x  = (const float*)d_in[0];
  const float* Wq = (const float*)d_in[1];
  const float* bq = (const float*)d_in[2];
  const float* Wk = (const float*)d_in[3];
  const float* bk = (const float*)d_in[4];
  const float* Wv = (const float*)d_in[5];
  const float* bv = (const float*)d_in[6];
  const float* Wo = (const float*)d_in[7];
  const float* bo = (const float*)d_in[8];
  const float* lsc = (const float*)d_in[9];
  // d_in[10] = mask: fixed causal triu(k=1), implemented analytically.

  uint8_t* w = (uint8_t*)d_ws;
  const size_t MB = 1ull << 20;
  bf16* xb   = (bf16*)(w + 0);          // 8 MB
  bf16* wqb  = (bf16*)(w + 8 * MB);     // 2 MB each
  bf16* wkb  = (bf16*)(w + 10 * MB);
  bf16* wvb  = (bf16*)(w + 12 * MB);
  bf16* wob  = (bf16*)(w + 14 * MB);
  bf16* qraw = (bf16*)(w + 16 * MB);    // 8 MB  bf16 [B,S,DIM]
  bf16* kraw = (bf16*)(w + 24 * MB);    // 8 MB
  bf16* qbn  = (bf16*)(w + 32 * MB);    // 8 MB  [B,H,S,64]
  bf16* kbn  = (bf16*)(w + 40 * MB);    // 8 MB
  bf16* vtb  = (bf16*)(w + 48 * MB);    // 8 MB  [B,H,64,S]
  bf16* atb  = (bf16*)(w + 56 * MB);    // 8 MB  [B,S,DIM]
  float* tc  = (float*)(w + 64 * MB);   // 256 KB
  float* ts  = (float*)(w + 64 * MB + 256 * 1024);

  cvt_kernel<<<4096, 256, 0, stream>>>(x, (unsigned short*)xb, Mn * DIMn / 4);
  cvt4_kernel<<<dim3(1024, 4), 256, 0, stream>>>(
      Wq, Wk, Wv, Wo, (unsigned short*)wqb, (unsigned short*)wkb,
      (unsigned short*)wvb, (unsigned short*)wob);
  rope_tab_kernel<<<256, 256, 0, stream>>>(tc, ts);

  qkv_kernel<<<dim3(32, 24), 256, 0, stream>>>(
      xb, wqb, wkb, wvb, bq, bk, bv,
      (unsigned short*)qraw, (unsigned short*)kraw, (unsigned short*)vtb);

  rope_norm_kernel<<<Mn * Hn * 2 / 8, 256, 0, stream>>>(
      (const unsigned short*)qraw, (const unsigned short*)kraw, tc, ts,
      (unsigned short*)qbn, (unsigned short*)kbn);

  attn_kernel<<<dim3(Sn / 64, Bn * Hn), 256, 0, stream>>>(qbn, kbn, vtb, lsc,
                                                          (unsigned short*)atb);

  gemm_bt_kernel<<<dim3(Mn / 128, DIMn / 128), 256, 0, stream>>>(atb, wob, bo, (float*)d_out);
}

// Round 4
// 135.900 us; speedup vs baseline: 2.5829x; 1.1135x over previous
//
#include <hip/hip_runtime.h>
#include <hip/hip_bf16.h>
#include <math.h>

typedef __hip_bfloat16 bf16;
typedef __attribute__((ext_vector_type(8))) short short8;
typedef __attribute__((ext_vector_type(4))) float floatx4;

static constexpr int Bn = 2, Sn = 2048, Hn = 16, DHn = 64, DIMn = 1024;
static constexpr int Mn = Bn * Sn;  // 4096 tokens

#if __has_builtin(__builtin_amdgcn_exp2f)
#define EXP2(x) __builtin_amdgcn_exp2f(x)
#else
#define EXP2(x) exp2f(x)
#endif

__device__ __forceinline__ unsigned short bfbits(float f) {
  union { __hip_bfloat16 h; unsigned short u; } cv;
  cv.h = __float2bfloat16(f);
  return cv.u;
}

__device__ __forceinline__ float bf2f(unsigned short u) {
  union { float f; unsigned int u; } cv;
  cv.u = ((unsigned int)u) << 16;
  return cv.f;
}

// async global->LDS, 16B per lane. dst is wave-uniform base; HW adds lane*16.
__device__ __forceinline__ void gload_lds16(const void* g, void* l) {
  __builtin_amdgcn_global_load_lds(
      (const __attribute__((address_space(1))) uint32_t*)g,
      (__attribute__((address_space(3))) uint32_t*)l, 16, 0, 0);
}

// ---------------- f32 -> bf16 convert (vectorized, 4/thread) ----------------
__global__ void cvt_kernel(const float* __restrict__ src, unsigned short* __restrict__ dst, int n4) {
  int i = blockIdx.x * blockDim.x + threadIdx.x;
  if (i >= n4) return;
  float4 v = ((const float4*)src)[i];
  ushort4 o;
  o.x = bfbits(v.x); o.y = bfbits(v.y); o.z = bfbits(v.z); o.w = bfbits(v.w);
  ((ushort4*)dst)[i] = o;
}

// 4 weight matrices (1M elems each) in one launch: grid (1024, 4)
__global__ void cvt4_kernel(const float* __restrict__ a0, const float* __restrict__ a1,
                            const float* __restrict__ a2, const float* __restrict__ a3,
                            unsigned short* __restrict__ o0, unsigned short* __restrict__ o1,
                            unsigned short* __restrict__ o2, unsigned short* __restrict__ o3) {
  const float* s = (blockIdx.y == 0) ? a0 : (blockIdx.y == 1) ? a1 : (blockIdx.y == 2) ? a2 : a3;
  unsigned short* d = (blockIdx.y == 0) ? o0 : (blockIdx.y == 1) ? o1 : (blockIdx.y == 2) ? o2 : o3;
  int i = blockIdx.x * 256 + threadIdx.x;
  float4 v = ((const float4*)s)[i];
  ushort4 o;
  o.x = bfbits(v.x); o.y = bfbits(v.y); o.z = bfbits(v.z); o.w = bfbits(v.w);
  ((ushort4*)d)[i] = o;
}

// ---------------- RoPE cos/sin tables: [S][32] ----------------
__global__ void rope_tab_kernel(float* __restrict__ tc, float* __restrict__ ts) {
  int t = blockIdx.x * 256 + threadIdx.x;  // 2048*32 = 65536
  int pos = t >> 5, i = t & 31;
  float f = powf(10000.0f, -(float)i * (1.0f / 32.0f));
  float a = (float)pos * f;
  tc[t] = cosf(a);
  ts[t] = sinf(a);
}

// ---------------- fused QKV GEMM ----------------
// grid (32, 24): blockIdx.y>>3 selects Q/K/V, (blockIdx.y&7)*128 = n0.
// Q,K: bf16 out [M][1024]. V: bf16 out transposed [B][H][64][S].
__global__ __launch_bounds__(256) void qkv_kernel(
    const bf16* __restrict__ A,
    const bf16* __restrict__ Wq, const bf16* __restrict__ Wk, const bf16* __restrict__ Wv,
    const float* __restrict__ bq, const float* __restrict__ bk, const float* __restrict__ bv,
    unsigned short* __restrict__ qo, unsigned short* __restrict__ ko,
    unsigned short* __restrict__ vt) {
  __shared__ bf16 sA[2][128 * 32];
  __shared__ bf16 sB[2][128 * 32];
  const int sel = blockIdx.y >> 3;
  const bf16* Bw = (sel == 0) ? Wq : (sel == 1) ? Wk : Wv;
  const float* bias = (sel == 0) ? bq : (sel == 1) ? bk : bv;
  const int tid = threadIdx.x;
  const int lane = tid & 63, wave = tid >> 6;
  const int wr = wave >> 1, wc = wave & 1;
  const int fr = lane & 15, fq = lane >> 4;
  const int m0 = blockIdx.x * 128, n0 = (blockIdx.y & 7) * 128;

  floatx4 acc[4][4] = {};
  const int sr = tid >> 2;
  const int sc8 = (tid & 3) * 8;

  auto stage = [&](int buf, int k0) {
#pragma unroll
    for (int call = 0; call < 2; ++call) {
      int row = call * 64 + sr;
      const bf16* ga = A + (size_t)(m0 + row) * 1024 + k0 + sc8;
      const bf16* gb = Bw + (size_t)(n0 + row) * 1024 + k0 + sc8;
      gload_lds16(ga, &sA[buf][call * 2048 + wave * 512]);
      gload_lds16(gb, &sB[buf][call * 2048 + wave * 512]);
    }
  };

  stage(0, 0);
  __syncthreads();
  int cur = 0;
  for (int k0 = 0; k0 < 1024; k0 += 32) {
    if (k0 + 32 < 1024) stage(cur ^ 1, k0 + 32);
    short8 af[4], bfr[4];
#pragma unroll
    for (int mi = 0; mi < 4; ++mi)
      af[mi] = *(const short8*)(&sA[cur][(wr * 64 + mi * 16 + fr) * 32 + fq * 8]);
#pragma unroll
    for (int ni = 0; ni < 4; ++ni)
      bfr[ni] = *(const short8*)(&sB[cur][(wc * 64 + ni * 16 + fr) * 32 + fq * 8]);
#pragma unroll
    for (int mi = 0; mi < 4; ++mi)
#pragma unroll
      for (int ni = 0; ni < 4; ++ni)
        acc[mi][ni] = __builtin_amdgcn_mfma_f32_16x16x32_bf16(af[mi], bfr[ni], acc[mi][ni], 0, 0, 0);
    __syncthreads();
    cur ^= 1;
  }

  unsigned short* dst = (sel == 0) ? qo : ko;
#pragma unroll
  for (int mi = 0; mi < 4; ++mi)
#pragma unroll
    for (int ni = 0; ni < 4; ++ni)
#pragma unroll
      for (int j = 0; j < 4; ++j) {
        int m = m0 + wr * 64 + mi * 16 + fq * 4 + j;
        int n = n0 + wc * 64 + ni * 16 + fr;
        float v = acc[mi][ni][j] + bias[n];
        if (sel < 2) {
          dst[(size_t)m * 1024 + n] = bfbits(v);
        } else {
          int b = m >> 11, s = m & 2047, h = n >> 6, d = n & 63;
          vt[(((size_t)b * 16 + h) * 64 + d) * 2048 + s] = bfbits(v);
        }
      }
}

// ---------------- Wo GEMM: f32 out ----------------
__global__ __launch_bounds__(256) void gemm_bt_kernel(
    const bf16* __restrict__ A, const bf16* __restrict__ Bw,
    const float* __restrict__ bias, float* __restrict__ Cf) {
  __shared__ bf16 sA[2][128 * 32];
  __shared__ bf16 sB[2][128 * 32];
  const int tid = threadIdx.x;
  const int lane = tid & 63, wave = tid >> 6;
  const int wr = wave >> 1, wc = wave & 1;
  const int fr = lane & 15, fq = lane >> 4;
  const int m0 = blockIdx.x * 128, n0 = blockIdx.y * 128;

  floatx4 acc[4][4] = {};
  const int sr = tid >> 2;
  const int sc8 = (tid & 3) * 8;

  auto stage = [&](int buf, int k0) {
#pragma unroll
    for (int call = 0; call < 2; ++call) {
      int row = call * 64 + sr;
      gload_lds16(A + (size_t)(m0 + row) * 1024 + k0 + sc8, &sA[buf][call * 2048 + wave * 512]);
      gload_lds16(Bw + (size_t)(n0 + row) * 1024 + k0 + sc8, &sB[buf][call * 2048 + wave * 512]);
    }
  };

  stage(0, 0);
  __syncthreads();
  int cur = 0;
  for (int k0 = 0; k0 < 1024; k0 += 32) {
    if (k0 + 32 < 1024) stage(cur ^ 1, k0 + 32);
    short8 af[4], bfr[4];
#pragma unroll
    for (int mi = 0; mi < 4; ++mi)
      af[mi] = *(const short8*)(&sA[cur][(wr * 64 + mi * 16 + fr) * 32 + fq * 8]);
#pragma unroll
    for (int ni = 0; ni < 4; ++ni)
      bfr[ni] = *(const short8*)(&sB[cur][(wc * 64 + ni * 16 + fr) * 32 + fq * 8]);
#pragma unroll
    for (int mi = 0; mi < 4; ++mi)
#pragma unroll
      for (int ni = 0; ni < 4; ++ni)
        acc[mi][ni] = __builtin_amdgcn_mfma_f32_16x16x32_bf16(af[mi], bfr[ni], acc[mi][ni], 0, 0, 0);
    __syncthreads();
    cur ^= 1;
  }

#pragma unroll
  for (int mi = 0; mi < 4; ++mi)
#pragma unroll
    for (int ni = 0; ni < 4; ++ni)
#pragma unroll
      for (int j = 0; j < 4; ++j) {
        int m = m0 + wr * 64 + mi * 16 + fq * 4 + j;
        int n = n0 + wc * 64 + ni * 16 + fr;
        Cf[(size_t)m * 1024 + n] = acc[mi][ni][j] + bias[n];
      }
}

// ---------------- RoPE + l2norm: bf16 [B,S,H,64] -> bf16 [B,H,S,64] ----------------
__global__ __launch_bounds__(256) void rope_norm_kernel(
    const unsigned short* __restrict__ qf, const unsigned short* __restrict__ kf,
    const float* __restrict__ tc, const float* __restrict__ ts,
    unsigned short* __restrict__ qb, unsigned short* __restrict__ kb) {
  int gr = blockIdx.x * 8 + (threadIdx.x >> 5);  // row id over 2*65536
  int j = threadIdx.x & 31;                      // pair index within head dim
  const unsigned short* src;
  unsigned short* dst;
  int rr;
  if (gr < Mn * Hn) { src = qf; dst = qb; rr = gr; }
  else { src = kf; dst = kb; rr = gr - Mn * Hn; }
  int h = rr & 15, bs = rr >> 4;
  int s = bs & 2047, b = bs >> 11;
  ushort2 xr = *(const ushort2*)(src + (size_t)bs * 1024 + h * 64 + 2 * j);
  float x0 = bf2f(xr.x), x1 = bf2f(xr.y);
  float c = tc[s * 32 + j], sn = ts[s * 32 + j];
  float y0 = x0 * c - x1 * sn;
  float y1 = x1 * c + x0 * sn;
  float ssq = y0 * y0 + y1 * y1;
#pragma unroll
  for (int msk = 1; msk < 32; msk <<= 1) ssq += __shfl_xor(ssq, msk);
  float inv = rsqrtf(ssq + 1e-6f);
  size_t o = (((size_t)b * 16 + h) * 2048 + s) * 64 + 2 * j;
  ushort2 pk;
  pk.x = bfbits(y0 * inv);
  pk.y = bfbits(y1 * inv);
  *(ushort2*)(dst + o) = pk;
}

// ---------------- causal flash attention, paired q-tiles ----------------
// grid (16, 32): block owns q-tiles qtA=bid.x, qtB=31-bid.x (constant total
// active work = 33 substeps). 4 waves x 16 q-rows per tile. KV staged 128
// rows/iter (2 substeps of 64), shared by both q-tiles.
__global__ __launch_bounds__(256, 2) void attn_kernel(
    const bf16* __restrict__ qb, const bf16* __restrict__ kb, const bf16* __restrict__ vt,
    const float* __restrict__ ls, unsigned short* __restrict__ out) {
  __shared__ bf16 sK[2][128 * 64];   // [kv 128][d 64], 128B rows, swz (row&7)<<4
  __shared__ bf16 sV[2][64 * 128];   // [d 64][kv 128], 256B rows, swz (row&15)<<4
  __shared__ char p_lds[4][2][2048]; // per wave, per tile-letter: 16x64 bf16
  const int qtA = blockIdx.x, qtB = 31 - (int)blockIdx.x;
  const int q0A = qtA * 64, q0B = qtB * 64;
  const int bh = blockIdx.y;
  const int tid = threadIdx.x;
  const int lane = tid & 63, wave = tid >> 6;
  const int fr = lane & 15, fq = lane >> 4;
  const float scl2 = __expf(ls[0]) * 0.125f * 1.44269504f;

  const size_t qbase = (size_t)bh * 2048;
  const size_t qrA = qbase + q0A + wave * 16 + fr;
  const size_t qrB = qbase + q0B + wave * 16 + fr;
  short8 qfA0 = *(const short8*)(qb + qrA * 64 + fq * 8);
  short8 qfA1 = *(const short8*)(qb + qrA * 64 + 32 + fq * 8);
  short8 qfB0 = *(const short8*)(qb + qrB * 64 + fq * 8);
  short8 qfB1 = *(const short8*)(qb + qrB * 64 + 32 + fq * 8);

  const bf16* kgb = kb + (size_t)bh * 2048 * 64;
  const bf16* vgb = vt + (size_t)bh * 64 * 2048;

  auto stage = [&](int buf, int t0) {
    // K: 128 rows x 128B
#pragma unroll
    for (int call = 0; call < 4; ++call) {
      int row = call * 32 + (tid >> 3);
      int sb = ((tid & 7) * 16) ^ ((row & 7) << 4);
      gload_lds16(kgb + (size_t)(t0 + row) * 64 + sb / 2,
                  &sK[buf][call * 2048 + wave * 512]);
    }
    // V: 64 rows x 256B
#pragma unroll
    for (int call = 0; call < 4; ++call) {
      int row = call * 16 + (tid >> 4);
      int sb = ((tid & 15) * 16) ^ ((row & 15) << 4);
      gload_lds16(vgb + (size_t)row * 2048 + t0 + sb / 2,
                  &sV[buf][call * 2048 + wave * 512]);
    }
  };

  floatx4 oaccA[4] = {}, oaccB[4] = {};
  float mb2A[4], lrA[4], mb2B[4], lrB[4];
#pragma unroll
  for (int r = 0; r < 4; ++r) {
    mb2A[r] = -INFINITY; lrA[r] = 0.f;
    mb2B[r] = -INFINITY; lrB[r] = 0.f;
  }
  const int rowqA = q0A + wave * 16 + fq * 4;
  const int rowqB = q0B + wave * 16 + fq * 4;
  const int sw = (fr & 7) << 4;
  char* pwA = p_lds[wave][0];
  char* pwB = p_lds[wave][1];
  short8 onesf;
#pragma unroll
  for (int i = 0; i < 8; ++i) onesf[i] = 0x3F80;  // bf16 1.0

  // softmax for one tile-letter over one 64-kv substep; writes P to pw.
  auto softmax_p = [&](floatx4* sacc, float* mb2, float* lrun, floatx4* oacc,
                       char* pw, int tk, int rowq, bool diag) {
    if (diag) {
#pragma unroll
      for (int c = 0; c < 4; ++c)
#pragma unroll
        for (int r = 0; r < 4; ++r)
          if ((tk + c * 16 + fr) > (rowq + r)) sacc[c][r] = -1e30f;
    }
    float pl[4];
#pragma unroll
    for (int r = 0; r < 4; ++r)
      pl[r] = fmaxf(fmaxf(sacc[0][r], sacc[1][r]), fmaxf(sacc[2][r], sacc[3][r]));
    float cmax = -INFINITY;
#pragma unroll
    for (int r = 0; r < 4; ++r) cmax = fmaxf(cmax, pl[r] * scl2 - mb2[r]);
    if (!__all(cmax <= 11.5f)) {
#pragma unroll
      for (int r = 0; r < 4; ++r) {
        float pm = pl[r];
#pragma unroll
        for (int msk = 1; msk < 16; msk <<= 1) pm = fmaxf(pm, __shfl_xor(pm, msk));
        float mnew = fmaxf(mb2[r], pm * scl2);
        float rs = EXP2(mb2[r] - mnew);
        mb2[r] = mnew;
        lrun[r] *= rs;
#pragma unroll
        for (int d = 0; d < 4; ++d) oacc[d][r] *= rs;
      }
    }
#pragma unroll
    for (int c = 0; c < 4; ++c)
#pragma unroll
      for (int r = 0; r < 4; ++r) {
        union { float f; unsigned int u; } pu;
        pu.f = EXP2(sacc[c][r] * scl2 - mb2[r]);
        int prow = fq * 4 + r;
        *(unsigned short*)(pw + prow * 128 + ((c * 32 + 2 * fr) ^ ((prow & 7) << 4))) =
            (unsigned short)(pu.u >> 16);
      }
  };

  stage(0, 0);
  __syncthreads();
  int cur = 0;
  for (int t0 = 0; t0 <= q0B; t0 += 128) {
    if (t0 + 128 <= q0B) stage(cur ^ 1, t0 + 128);
    const char* sKc = (const char*)sK[cur];
    const char* sVc = (const char*)sV[cur];
#pragma unroll
    for (int s = 0; s < 2; ++s) {
      const int tk = t0 + s * 64;
      if (tk > q0B) break;
      const bool actA = (tk <= q0A);
      floatx4 saccA[4] = {}, saccB[4] = {};
      __builtin_amdgcn_s_setprio(1);
#pragma unroll
      for (int c = 0; c < 4; ++c) {
        int rb = (s * 64 + c * 16 + fr) * 128;
        short8 kf0 = *(const short8*)(sKc + rb + ((fq * 16) ^ sw));
        short8 kf1 = *(const short8*)(sKc + rb + ((64 + fq * 16) ^ sw));
        saccB[c] = __builtin_amdgcn_mfma_f32_16x16x32_bf16(qfB0, kf0, saccB[c], 0, 0, 0);
        saccB[c] = __builtin_amdgcn_mfma_f32_16x16x32_bf16(qfB1, kf1, saccB[c], 0, 0, 0);
        if (actA) {
          saccA[c] = __builtin_amdgcn_mfma_f32_16x16x32_bf16(qfA0, kf0, saccA[c], 0, 0, 0);
          saccA[c] = __builtin_amdgcn_mfma_f32_16x16x32_bf16(qfA1, kf1, saccA[c], 0, 0, 0);
        }
      }
      __builtin_amdgcn_s_setprio(0);
      softmax_p(saccB, mb2B, lrB, oaccB, pwB, tk, rowqB, tk == q0B);
      if (actA) softmax_p(saccA, mb2A, lrA, oaccA, pwA, tk, rowqA, tk == q0A);

      short8 pB0 = *(const short8*)(pwB + fr * 128 + ((fq * 16) ^ sw));
      short8 pB1 = *(const short8*)(pwB + fr * 128 + ((64 + fq * 16) ^ sw));
      short8 pA0, pA1;
      if (actA) {
        pA0 = *(const short8*)(pwA + fr * 128 + ((fq * 16) ^ sw));
        pA1 = *(const short8*)(pwA + fr * 128 + ((64 + fq * 16) ^ sw));
      }
      __builtin_amdgcn_s_setprio(1);
      floatx4 tsB = {}, tsA = {};
      tsB = __builtin_amdgcn_mfma_f32_16x16x32_bf16(pB0, onesf, tsB, 0, 0, 0);
      tsB = __builtin_amdgcn_mfma_f32_16x16x32_bf16(pB1, onesf, tsB, 0, 0, 0);
      if (actA) {
        tsA = __builtin_amdgcn_mfma_f32_16x16x32_bf16(pA0, onesf, tsA, 0, 0, 0);
        tsA = __builtin_amdgcn_mfma_f32_16x16x32_bf16(pA1, onesf, tsA, 0, 0, 0);
      }
#pragma unroll
      for (int d = 0; d < 4; ++d) {
        int rb = (d * 16 + fr) * 256;
        short8 vf0 = *(const short8*)(sVc + rb + ((s * 128 + fq * 16) ^ (fr << 4)));
        short8 vf1 = *(const short8*)(sVc + rb + ((s * 128 + 64 + fq * 16) ^ (fr << 4)));
        oaccB[d] = __builtin_amdgcn_mfma_f32_16x16x32_bf16(pB0, vf0, oaccB[d], 0, 0, 0);
        oaccB[d] = __builtin_amdgcn_mfma_f32_16x16x32_bf16(pB1, vf1, oaccB[d], 0, 0, 0);
        if (actA) {
          oaccA[d] = __builtin_amdgcn_mfma_f32_16x16x32_bf16(pA0, vf0, oaccA[d], 0, 0, 0);
          oaccA[d] = __builtin_amdgcn_mfma_f32_16x16x32_bf16(pA1, vf1, oaccA[d], 0, 0, 0);
        }
      }
      __builtin_amdgcn_s_setprio(0);
#pragma unroll
      for (int r = 0; r < 4; ++r) {
        lrB[r] += tsB[r];
        if (actA) lrA[r] += tsA[r];
      }
    }
    __syncthreads();
    cur ^= 1;
  }
  const int b = bh >> 4, h = bh & 15;
#pragma unroll
  for (int r = 0; r < 4; ++r) {
    float ilA = 1.0f / lrA[r];
    float ilB = 1.0f / lrB[r];
#pragma unroll
    for (int d = 0; d < 4; ++d) {
      size_t oA = ((size_t)b * 2048 + rowqA + r) * 1024 + h * 64 + d * 16 + fr;
      size_t oB = ((size_t)b * 2048 + rowqB + r) * 1024 + h * 64 + d * 16 + fr;
      out[oA] = bfbits(oaccA[d][r] * ilA);
      out[oB] = bfbits(oaccB[d][r] * ilB);
    }
  }
}

extern "C" void kernel_launch(void* const* d_in, const int* in_sizes, int n_in,
                              void* d_out, int out_size, void* d_ws, size_t ws_size,
                              hipStream_t stream) {
  (void)in_sizes; (void)n_in; (void)out_size; (void)ws_size;
  const float* x  = (const float*)d_in[0];
  const float* Wq = (const float*)d_in[1];
  const float* bq = (const float*)d_in[2];
  const float* Wk = (const float*)d_in[3];
  const float* bk = (const float*)d_in[4];
  const float* Wv = (const float*)d_in[5];
  const float* bv = (const float*)d_in[6];
  const float* Wo = (const float*)d_in[7];
  const float* bo = (const float*)d_in[8];
  const float* lsc = (const float*)d_in[9];
  // d_in[10] = mask: fixed causal triu(k=1), implemented analytically.

  uint8_t* w = (uint8_t*)d_ws;
  const size_t MB = 1ull << 20;
  bf16* xb   = (bf16*)(w + 0);          // 8 MB
  bf16* wqb  = (bf16*)(w + 8 * MB);     // 2 MB each
  bf16* wkb  = (bf16*)(w + 10 * MB);
  bf16* wvb  = (bf16*)(w + 12 * MB);
  bf16* wob  = (bf16*)(w + 14 * MB);
  bf16* qraw = (bf16*)(w + 16 * MB);    // 8 MB  bf16 [B,S,DIM]
  bf16* kraw = (bf16*)(w + 24 * MB);    // 8 MB
  bf16* qbn  = (bf16*)(w + 32 * MB);    // 8 MB  [B,H,S,64]
  bf16* kbn  = (bf16*)(w + 40 * MB);    // 8 MB
  bf16* vtb  = (bf16*)(w + 48 * MB);    // 8 MB  [B,H,64,S]
  bf16* atb  = (bf16*)(w + 56 * MB);    // 8 MB  [B,S,DIM]
  float* tc  = (float*)(w + 64 * MB);   // 256 KB
  float* ts  = (float*)(w + 64 * MB + 256 * 1024);

  cvt_kernel<<<4096, 256, 0, stream>>>(x, (unsigned short*)xb, Mn * DIMn / 4);
  cvt4_kernel<<<dim3(1024, 4), 256, 0, stream>>>(
      Wq, Wk, Wv, Wo, (unsigned short*)wqb, (unsigned short*)wkb,
      (unsigned short*)wvb, (unsigned short*)wob);
  rope_tab_kernel<<<256, 256, 0, stream>>>(tc, ts);

  qkv_kernel<<<dim3(32, 24), 256, 0, stream>>>(
      xb, wqb, wkb, wvb, bq, bk, bv,
      (unsigned short*)qraw, (unsigned short*)kraw, (unsigned short*)vtb);

  rope_norm_kernel<<<Mn * Hn * 2 / 8, 256, 0, stream>>>(
      (const unsigned short*)qraw, (const unsigned short*)kraw, tc, ts,
      (unsigned short*)qbn, (unsigned short*)kbn);

  attn_kernel<<<dim3(16, Bn * Hn), 256, 0, stream>>>(qbn, kbn, vtb, lsc,
                                                     (unsigned short*)atb);

  gemm_bt_kernel<<<dim3(Mn / 128, DIMn / 128), 256, 0, stream>>>(atb, wob, bo, (float*)d_out);
}

// Round 5
// 134.438 us; speedup vs baseline: 2.6109x; 1.0109x over previous
//
#include <hip/hip_runtime.h>
#include <hip/hip_bf16.h>
#include <math.h>

typedef __hip_bfloat16 bf16;
typedef __attribute__((ext_vector_type(8))) short short8;
typedef __attribute__((ext_vector_type(4))) float floatx4;

static constexpr int Bn = 2, Sn = 2048, Hn = 16, DHn = 64, DIMn = 1024;
static constexpr int Mn = Bn * Sn;  // 4096 tokens

#if __has_builtin(__builtin_amdgcn_exp2f)
#define EXP2(x) __builtin_amdgcn_exp2f(x)
#else
#define EXP2(x) exp2f(x)
#endif

__device__ __forceinline__ unsigned short bfbits(float f) {
  union { __hip_bfloat16 h; unsigned short u; } cv;
  cv.h = __float2bfloat16(f);
  return cv.u;
}

__device__ __forceinline__ float bf2f(unsigned short u) {
  union { float f; unsigned int u; } cv;
  cv.u = ((unsigned int)u) << 16;
  return cv.f;
}

// async global->LDS, 16B per lane. dst is wave-uniform base; HW adds lane*16.
__device__ __forceinline__ void gload_lds16(const void* g, void* l) {
  __builtin_amdgcn_global_load_lds(
      (const __attribute__((address_space(1))) uint32_t*)g,
      (__attribute__((address_space(3))) uint32_t*)l, 16, 0, 0);
}

// ---------------- f32 -> bf16 convert (vectorized, 4/thread) ----------------
__global__ void cvt_kernel(const float* __restrict__ src, unsigned short* __restrict__ dst, int n4) {
  int i = blockIdx.x * blockDim.x + threadIdx.x;
  if (i >= n4) return;
  float4 v = ((const float4*)src)[i];
  ushort4 o;
  o.x = bfbits(v.x); o.y = bfbits(v.y); o.z = bfbits(v.z); o.w = bfbits(v.w);
  ((ushort4*)dst)[i] = o;
}

// 4 weight matrices (1M elems each) in one launch: grid (1024, 4)
__global__ void cvt4_kernel(const float* __restrict__ a0, const float* __restrict__ a1,
                            const float* __restrict__ a2, const float* __restrict__ a3,
                            unsigned short* __restrict__ o0, unsigned short* __restrict__ o1,
                            unsigned short* __restrict__ o2, unsigned short* __restrict__ o3) {
  const float* s = (blockIdx.y == 0) ? a0 : (blockIdx.y == 1) ? a1 : (blockIdx.y == 2) ? a2 : a3;
  unsigned short* d = (blockIdx.y == 0) ? o0 : (blockIdx.y == 1) ? o1 : (blockIdx.y == 2) ? o2 : o3;
  int i = blockIdx.x * 256 + threadIdx.x;
  float4 v = ((const float4*)s)[i];
  ushort4 o;
  o.x = bfbits(v.x); o.y = bfbits(v.y); o.z = bfbits(v.z); o.w = bfbits(v.w);
  ((ushort4*)d)[i] = o;
}

// ---------------- RoPE cos/sin tables: [S][32] ----------------
__global__ void rope_tab_kernel(float* __restrict__ tc, float* __restrict__ ts) {
  int t = blockIdx.x * 256 + threadIdx.x;  // 2048*32 = 65536
  int pos = t >> 5, i = t & 31;
  float f = powf(10000.0f, -(float)i * (1.0f / 32.0f));
  float a = (float)pos * f;
  tc[t] = cosf(a);
  ts[t] = sinf(a);
}

// ---------------- fused QKV GEMM ----------------
// grid (32, 24): blockIdx.y>>3 selects Q/K/V, (blockIdx.y&7)*128 = n0.
// Q,K: bf16 out [M][1024]. V: bf16 out transposed [B][H][64][S].
__global__ __launch_bounds__(256) void qkv_kernel(
    const bf16* __restrict__ A,
    const bf16* __restrict__ Wq, const bf16* __restrict__ Wk, const bf16* __restrict__ Wv,
    const float* __restrict__ bq, const float* __restrict__ bk, const float* __restrict__ bv,
    unsigned short* __restrict__ qo, unsigned short* __restrict__ ko,
    unsigned short* __restrict__ vt) {
  __shared__ bf16 sA[2][128 * 32];
  __shared__ bf16 sB[2][128 * 32];
  const int sel = blockIdx.y >> 3;
  const bf16* Bw = (sel == 0) ? Wq : (sel == 1) ? Wk : Wv;
  const float* bias = (sel == 0) ? bq : (sel == 1) ? bk : bv;
  const int tid = threadIdx.x;
  const int lane = tid & 63, wave = tid >> 6;
  const int wr = wave >> 1, wc = wave & 1;
  const int fr = lane & 15, fq = lane >> 4;
  const int m0 = blockIdx.x * 128, n0 = (blockIdx.y & 7) * 128;

  floatx4 acc[4][4] = {};
  const int sr = tid >> 2;
  const int sc8 = (tid & 3) * 8;

  auto stage = [&](int buf, int k0) {
#pragma unroll
    for (int call = 0; call < 2; ++call) {
      int row = call * 64 + sr;
      const bf16* ga = A + (size_t)(m0 + row) * 1024 + k0 + sc8;
      const bf16* gb = Bw + (size_t)(n0 + row) * 1024 + k0 + sc8;
      gload_lds16(ga, &sA[buf][call * 2048 + wave * 512]);
      gload_lds16(gb, &sB[buf][call * 2048 + wave * 512]);
    }
  };

  stage(0, 0);
  __syncthreads();
  int cur = 0;
  for (int k0 = 0; k0 < 1024; k0 += 32) {
    if (k0 + 32 < 1024) stage(cur ^ 1, k0 + 32);
    short8 af[4], bfr[4];
#pragma unroll
    for (int mi = 0; mi < 4; ++mi)
      af[mi] = *(const short8*)(&sA[cur][(wr * 64 + mi * 16 + fr) * 32 + fq * 8]);
#pragma unroll
    for (int ni = 0; ni < 4; ++ni)
      bfr[ni] = *(const short8*)(&sB[cur][(wc * 64 + ni * 16 + fr) * 32 + fq * 8]);
#pragma unroll
    for (int mi = 0; mi < 4; ++mi)
#pragma unroll
      for (int ni = 0; ni < 4; ++ni)
        acc[mi][ni] = __builtin_amdgcn_mfma_f32_16x16x32_bf16(af[mi], bfr[ni], acc[mi][ni], 0, 0, 0);
    __syncthreads();
    cur ^= 1;
  }

  unsigned short* dst = (sel == 0) ? qo : ko;
#pragma unroll
  for (int mi = 0; mi < 4; ++mi)
#pragma unroll
    for (int ni = 0; ni < 4; ++ni)
#pragma unroll
      for (int j = 0; j < 4; ++j) {
        int m = m0 + wr * 64 + mi * 16 + fq * 4 + j;
        int n = n0 + wc * 64 + ni * 16 + fr;
        float v = acc[mi][ni][j] + bias[n];
        if (sel < 2) {
          dst[(size_t)m * 1024 + n] = bfbits(v);
        } else {
          int b = m >> 11, s = m & 2047, h = n >> 6, d = n & 63;
          vt[(((size_t)b * 16 + h) * 64 + d) * 2048 + s] = bfbits(v);
        }
      }
}

// ---------------- Wo GEMM: f32 out ----------------
__global__ __launch_bounds__(256) void gemm_bt_kernel(
    const bf16* __restrict__ A, const bf16* __restrict__ Bw,
    const float* __restrict__ bias, float* __restrict__ Cf) {
  __shared__ bf16 sA[2][128 * 32];
  __shared__ bf16 sB[2][128 * 32];
  const int tid = threadIdx.x;
  const int lane = tid & 63, wave = tid >> 6;
  const int wr = wave >> 1, wc = wave & 1;
  const int fr = lane & 15, fq = lane >> 4;
  const int m0 = blockIdx.x * 128, n0 = blockIdx.y * 128;

  floatx4 acc[4][4] = {};
  const int sr = tid >> 2;
  const int sc8 = (tid & 3) * 8;

  auto stage = [&](int buf, int k0) {
#pragma unroll
    for (int call = 0; call < 2; ++call) {
      int row = call * 64 + sr;
      gload_lds16(A + (size_t)(m0 + row) * 1024 + k0 + sc8, &sA[buf][call * 2048 + wave * 512]);
      gload_lds16(Bw + (size_t)(n0 + row) * 1024 + k0 + sc8, &sB[buf][call * 2048 + wave * 512]);
    }
  };

  stage(0, 0);
  __syncthreads();
  int cur = 0;
  for (int k0 = 0; k0 < 1024; k0 += 32) {
    if (k0 + 32 < 1024) stage(cur ^ 1, k0 + 32);
    short8 af[4], bfr[4];
#pragma unroll
    for (int mi = 0; mi < 4; ++mi)
      af[mi] = *(const short8*)(&sA[cur][(wr * 64 + mi * 16 + fr) * 32 + fq * 8]);
#pragma unroll
    for (int ni = 0; ni < 4; ++ni)
      bfr[ni] = *(const short8*)(&sB[cur][(wc * 64 + ni * 16 + fr) * 32 + fq * 8]);
#pragma unroll
    for (int mi = 0; mi < 4; ++mi)
#pragma unroll
      for (int ni = 0; ni < 4; ++ni)
        acc[mi][ni] = __builtin_amdgcn_mfma_f32_16x16x32_bf16(af[mi], bfr[ni], acc[mi][ni], 0, 0, 0);
    __syncthreads();
    cur ^= 1;
  }

#pragma unroll
  for (int mi = 0; mi < 4; ++mi)
#pragma unroll
    for (int ni = 0; ni < 4; ++ni)
#pragma unroll
      for (int j = 0; j < 4; ++j) {
        int m = m0 + wr * 64 + mi * 16 + fq * 4 + j;
        int n = n0 + wc * 64 + ni * 16 + fr;
        Cf[(size_t)m * 1024 + n] = acc[mi][ni][j] + bias[n];
      }
}

// ---------------- RoPE + l2norm: bf16 [B,S,H,64] -> bf16 [B,H,S,64] ----------------
__global__ __launch_bounds__(256) void rope_norm_kernel(
    const unsigned short* __restrict__ qf, const unsigned short* __restrict__ kf,
    const float* __restrict__ tc, const float* __restrict__ ts,
    unsigned short* __restrict__ qb, unsigned short* __restrict__ kb) {
  int gr = blockIdx.x * 8 + (threadIdx.x >> 5);  // row id over 2*65536
  int j = threadIdx.x & 31;                      // pair index within head dim
  const unsigned short* src;
  unsigned short* dst;
  int rr;
  if (gr < Mn * Hn) { src = qf; dst = qb; rr = gr; }
  else { src = kf; dst = kb; rr = gr - Mn * Hn; }
  int h = rr & 15, bs = rr >> 4;
  int s = bs & 2047, b = bs >> 11;
  ushort2 xr = *(const ushort2*)(src + (size_t)bs * 1024 + h * 64 + 2 * j);
  float x0 = bf2f(xr.x), x1 = bf2f(xr.y);
  float c = tc[s * 32 + j], sn = ts[s * 32 + j];
  float y0 = x0 * c - x1 * sn;
  float y1 = x1 * c + x0 * sn;
  float ssq = y0 * y0 + y1 * y1;
#pragma unroll
  for (int msk = 1; msk < 32; msk <<= 1) ssq += __shfl_xor(ssq, msk);
  float inv = rsqrtf(ssq + 1e-6f);
  size_t o = (((size_t)b * 16 + h) * 2048 + s) * 64 + 2 * j;
  ushort2 pk;
  pk.x = bfbits(y0 * inv);
  pk.y = bfbits(y1 * inv);
  *(ushort2*)(dst + o) = pk;
}

// ---------------- causal flash attention, split-letter paired q-tiles ----------------
// grid (32, 32): block owns 32-row q-tiles qtA=bid.x (waves 0,1) and
// qtB=63-bid.x (waves 2,3). Each wave: one letter, 16 q-rows — single-letter
// serial chain. KVBLK=64 double-buffered, staged once for both letters.
// LDS 40KB -> 4 blocks/CU -> 16 waves/CU.
__global__ __launch_bounds__(256, 4) void attn_kernel(
    const bf16* __restrict__ qb, const bf16* __restrict__ kb, const bf16* __restrict__ vt,
    const float* __restrict__ ls, unsigned short* __restrict__ out) {
  __shared__ bf16 sK[2][64 * 64];   // [kv][d], 128B rows, swz (row&7)<<4
  __shared__ bf16 sV[2][64 * 64];   // [d][kv], 128B rows, swz (row&7)<<4
  __shared__ char p_lds[4][2048];   // per wave: 16x64 bf16, swz (prow&7)<<4
  const int q0A = blockIdx.x * 32, q0B = (63 - (int)blockIdx.x) * 32;
  const int bh = blockIdx.y;
  const int tid = threadIdx.x;
  const int lane = tid & 63, wave = tid >> 6;
  const int fr = lane & 15, fq = lane >> 4;
  const int myq0 = (wave >= 2) ? q0B : q0A;
  const int base = myq0 + (wave & 1) * 16;   // first q-row of this wave
  const float scl2 = __expf(ls[0]) * 0.125f * 1.44269504f;

  const size_t qrow = (size_t)bh * 2048 + base + fr;
  short8 qf0 = *(const short8*)(qb + qrow * 64 + fq * 8);
  short8 qf1 = *(const short8*)(qb + qrow * 64 + 32 + fq * 8);

  const bf16* kgb = kb + (size_t)bh * 2048 * 64;
  const bf16* vgb = vt + (size_t)bh * 64 * 2048;

  auto stage = [&](int buf, int t0) {
#pragma unroll
    for (int call = 0; call < 2; ++call) {
      int row = call * 32 + (tid >> 3);
      int sb = ((tid & 7) * 16) ^ ((row & 7) << 4);
      gload_lds16(kgb + (size_t)(t0 + row) * 64 + sb / 2,
                  &sK[buf][call * 2048 + wave * 512]);
    }
#pragma unroll
    for (int call = 0; call < 2; ++call) {
      int row = call * 32 + (tid >> 3);
      int sb = ((tid & 7) * 16) ^ ((row & 7) << 4);
      gload_lds16(vgb + (size_t)row * 2048 + t0 + sb / 2,
                  &sV[buf][call * 2048 + wave * 512]);
    }
  };

  floatx4 oacc[4] = {};
  float mb2[4], lrun[4];
#pragma unroll
  for (int r = 0; r < 4; ++r) { mb2[r] = -INFINITY; lrun[r] = 0.f; }
  const int rowq = base + fq * 4;            // + r
  const int sw = (fr & 7) << 4;
  char* pw = p_lds[wave];
  short8 onesf;
#pragma unroll
  for (int i = 0; i < 8; ++i) onesf[i] = 0x3F80;  // bf16 1.0

  stage(0, 0);
  __syncthreads();
  int cur = 0;
  const int tEnd = q0B + 32;
  for (int t0 = 0; t0 < tEnd; t0 += 64) {
    if (t0 + 64 < tEnd) stage(cur ^ 1, t0 + 64);
    if (t0 < myq0 + 32) {  // this wave's letter still active
      const char* sKc = (const char*)sK[cur];
      const char* sVc = (const char*)sV[cur];
      floatx4 sacc[4] = {};
      __builtin_amdgcn_s_setprio(1);
#pragma unroll
      for (int c = 0; c < 4; ++c) {
        int rb = (c * 16 + fr) * 128;
        short8 kf0 = *(const short8*)(sKc + rb + ((fq * 16) ^ sw));
        short8 kf1 = *(const short8*)(sKc + rb + ((64 + fq * 16) ^ sw));
        sacc[c] = __builtin_amdgcn_mfma_f32_16x16x32_bf16(qf0, kf0, sacc[c], 0, 0, 0);
        sacc[c] = __builtin_amdgcn_mfma_f32_16x16x32_bf16(qf1, kf1, sacc[c], 0, 0, 0);
      }
      __builtin_amdgcn_s_setprio(0);
      if (t0 + 63 > rowq) {  // causal mask needed on this substep
#pragma unroll
        for (int c = 0; c < 4; ++c)
#pragma unroll
          for (int r = 0; r < 4; ++r)
            if ((t0 + c * 16 + fr) > (rowq + r)) sacc[c][r] = -1e30f;
      }
      float pl[4];
#pragma unroll
      for (int r = 0; r < 4; ++r)
        pl[r] = fmaxf(fmaxf(sacc[0][r], sacc[1][r]), fmaxf(sacc[2][r], sacc[3][r]));
      float cmax = -INFINITY;
#pragma unroll
      for (int r = 0; r < 4; ++r) cmax = fmaxf(cmax, pl[r] * scl2 - mb2[r]);
      if (!__all(cmax <= 11.5f)) {  // slow path: full row-max + rescale
#pragma unroll
        for (int r = 0; r < 4; ++r) {
          float pm = pl[r];
#pragma unroll
          for (int msk = 1; msk < 16; msk <<= 1) pm = fmaxf(pm, __shfl_xor(pm, msk));
          float mnew = fmaxf(mb2[r], pm * scl2);
          float rs = EXP2(mb2[r] - mnew);
          mb2[r] = mnew;
          lrun[r] *= rs;
#pragma unroll
          for (int d = 0; d < 4; ++d) oacc[d][r] *= rs;
        }
      }
#pragma unroll
      for (int c = 0; c < 4; ++c)
#pragma unroll
        for (int r = 0; r < 4; ++r) {
          union { float f; unsigned int u; } pu;
          pu.f = EXP2(sacc[c][r] * scl2 - mb2[r]);
          int prow = fq * 4 + r;
          *(unsigned short*)(pw + prow * 128 + ((c * 32 + 2 * fr) ^ ((prow & 7) << 4))) =
              (unsigned short)(pu.u >> 16);
        }
      short8 pf0 = *(const short8*)(pw + fr * 128 + ((fq * 16) ^ sw));
      short8 pf1 = *(const short8*)(pw + fr * 128 + ((64 + fq * 16) ^ sw));
      __builtin_amdgcn_s_setprio(1);
      floatx4 tsum = {};
      tsum = __builtin_amdgcn_mfma_f32_16x16x32_bf16(pf0, onesf, tsum, 0, 0, 0);
      tsum = __builtin_amdgcn_mfma_f32_16x16x32_bf16(pf1, onesf, tsum, 0, 0, 0);
#pragma unroll
      for (int d = 0; d < 4; ++d) {
        int rb = (d * 16 + fr) * 128;
        short8 vf0 = *(const short8*)(sVc + rb + ((fq * 16) ^ sw));
        short8 vf1 = *(const short8*)(sVc + rb + ((64 + fq * 16) ^ sw));
        oacc[d] = __builtin_amdgcn_mfma_f32_16x16x32_bf16(pf0, vf0, oacc[d], 0, 0, 0);
        oacc[d] = __builtin_amdgcn_mfma_f32_16x16x32_bf16(pf1, vf1, oacc[d], 0, 0, 0);
      }
      __builtin_amdgcn_s_setprio(0);
#pragma unroll
      for (int r = 0; r < 4; ++r) lrun[r] += tsum[r];
    }
    __syncthreads();
    cur ^= 1;
  }
  const int b = bh >> 4, h = bh & 15;
#pragma unroll
  for (int r = 0; r < 4; ++r) {
    float il = 1.0f / lrun[r];
#pragma unroll
    for (int d = 0; d < 4; ++d) {
      size_t o = ((size_t)b * 2048 + rowq + r) * 1024 + h * 64 + d * 16 + fr;
      out[o] = bfbits(oacc[d][r] * il);
    }
  }
}

extern "C" void kernel_launch(void* const* d_in, const int* in_sizes, int n_in,
                              void* d_out, int out_size, void* d_ws, size_t ws_size,
                              hipStream_t stream) {
  (void)in_sizes; (void)n_in; (void)out_size; (void)ws_size;
  const float* x  = (const float*)d_in[0];
  const float* Wq = (const float*)d_in[1];
  const float* bq = (const float*)d_in[2];
  const float* Wk = (const float*)d_in[3];
  const float* bk = (const float*)d_in[4];
  const float* Wv = (const float*)d_in[5];
  const float* bv = (const float*)d_in[6];
  const float* Wo = (const float*)d_in[7];
  const float* bo = (const float*)d_in[8];
  const float* lsc = (const float*)d_in[9];
  // d_in[10] = mask: fixed causal triu(k=1), implemented analytically.

  uint8_t* w = (uint8_t*)d_ws;
  const size_t MB = 1ull << 20;
  bf16* xb   = (bf16*)(w + 0);          // 8 MB
  bf16* wqb  = (bf16*)(w + 8 * MB);     // 2 MB each
  bf16* wkb  = (bf16*)(w + 10 * MB);
  bf16* wvb  = (bf16*)(w + 12 * MB);
  bf16* wob  = (bf16*)(w + 14 * MB);
  bf16* qraw = (bf16*)(w + 16 * MB);    // 8 MB  bf16 [B,S,DIM]
  bf16* kraw = (bf16*)(w + 24 * MB);    // 8 MB
  bf16* qbn  = (bf16*)(w + 32 * MB);    // 8 MB  [B,H,S,64]
  bf16* kbn  = (bf16*)(w + 40 * MB);    // 8 MB
  bf16* vtb  = (bf16*)(w + 48 * MB);    // 8 MB  [B,H,64,S]
  bf16* atb  = (bf16*)(w + 56 * MB);    // 8 MB  [B,S,DIM]
  float* tc  = (float*)(w + 64 * MB);   // 256 KB
  float* ts  = (float*)(w + 64 * MB + 256 * 1024);

  cvt_kernel<<<4096, 256, 0, stream>>>(x, (unsigned short*)xb, Mn * DIMn / 4);
  cvt4_kernel<<<dim3(1024, 4), 256, 0, stream>>>(
      Wq, Wk, Wv, Wo, (unsigned short*)wqb, (unsigned short*)wkb,
      (unsigned short*)wvb, (unsigned short*)wob);
  rope_tab_kernel<<<256, 256, 0, stream>>>(tc, ts);

  qkv_kernel<<<dim3(32, 24), 256, 0, stream>>>(
      xb, wqb, wkb, wvb, bq, bk, bv,
      (unsigned short*)qraw, (unsigned short*)kraw, (unsigned short*)vtb);

  rope_norm_kernel<<<Mn * Hn * 2 / 8, 256, 0, stream>>>(
      (const unsigned short*)qraw, (const unsigned short*)kraw, tc, ts,
      (unsigned short*)qbn, (unsigned short*)kbn);

  attn_kernel<<<dim3(32, Bn * Hn), 256, 0, stream>>>(qbn, kbn, vtb, lsc,
                                                     (unsigned short*)atb);

  gemm_bt_kernel<<<dim3(Mn / 128, DIMn / 128), 256, 0, stream>>>(atb, wob, bo, (float*)d_out);
}

// Round 6
// 132.946 us; speedup vs baseline: 2.6402x; 1.0112x over previous
//
#include <hip/hip_runtime.h>
#include <hip/hip_bf16.h>
#include <math.h>

typedef __hip_bfloat16 bf16;
typedef __attribute__((ext_vector_type(8))) short short8;
typedef __attribute__((ext_vector_type(4))) float floatx4;

static constexpr int Bn = 2, Sn = 2048, Hn = 16, DHn = 64, DIMn = 1024;
static constexpr int Mn = Bn * Sn;  // 4096 tokens

#if __has_builtin(__builtin_amdgcn_exp2f)
#define EXP2(x) __builtin_amdgcn_exp2f(x)
#else
#define EXP2(x) exp2f(x)
#endif

__device__ __forceinline__ unsigned short bfbits(float f) {
  union { __hip_bfloat16 h; unsigned short u; } cv;
  cv.h = __float2bfloat16(f);
  return cv.u;
}

__device__ __forceinline__ float bf2f(unsigned short u) {
  union { float f; unsigned int u; } cv;
  cv.u = ((unsigned int)u) << 16;
  return cv.f;
}

// async global->LDS, 16B per lane. dst is wave-uniform base; HW adds lane*16.
__device__ __forceinline__ void gload_lds16(const void* g, void* l) {
  __builtin_amdgcn_global_load_lds(
      (const __attribute__((address_space(1))) uint32_t*)g,
      (__attribute__((address_space(3))) uint32_t*)l, 16, 0, 0);
}

// counted waits (T4). sched_barrier pins per rule #18.
__device__ __forceinline__ void wait_vm4() {
  asm volatile("s_waitcnt vmcnt(4)" ::: "memory");
  __builtin_amdgcn_sched_barrier(0);
}
__device__ __forceinline__ void wait_vm0() {
  asm volatile("s_waitcnt vmcnt(0)" ::: "memory");
  __builtin_amdgcn_sched_barrier(0);
}

// ---------------- f32 -> bf16 convert (vectorized, 4/thread) ----------------
__global__ void cvt_kernel(const float* __restrict__ src, unsigned short* __restrict__ dst, int n4) {
  int i = blockIdx.x * blockDim.x + threadIdx.x;
  if (i >= n4) return;
  float4 v = ((const float4*)src)[i];
  ushort4 o;
  o.x = bfbits(v.x); o.y = bfbits(v.y); o.z = bfbits(v.z); o.w = bfbits(v.w);
  ((ushort4*)dst)[i] = o;
}

// 4 weight matrices (1M elems each) in one launch: grid (1024, 4)
__global__ void cvt4_kernel(const float* __restrict__ a0, const float* __restrict__ a1,
                            const float* __restrict__ a2, const float* __restrict__ a3,
                            unsigned short* __restrict__ o0, unsigned short* __restrict__ o1,
                            unsigned short* __restrict__ o2, unsigned short* __restrict__ o3) {
  const float* s = (blockIdx.y == 0) ? a0 : (blockIdx.y == 1) ? a1 : (blockIdx.y == 2) ? a2 : a3;
  unsigned short* d = (blockIdx.y == 0) ? o0 : (blockIdx.y == 1) ? o1 : (blockIdx.y == 2) ? o2 : o3;
  int i = blockIdx.x * 256 + threadIdx.x;
  float4 v = ((const float4*)s)[i];
  ushort4 o;
  o.x = bfbits(v.x); o.y = bfbits(v.y); o.z = bfbits(v.z); o.w = bfbits(v.w);
  ((ushort4*)d)[i] = o;
}

// ---------------- RoPE cos/sin tables: [S][32] ----------------
__global__ void rope_tab_kernel(float* __restrict__ tc, float* __restrict__ ts) {
  int t = blockIdx.x * 256 + threadIdx.x;  // 2048*32 = 65536
  int pos = t >> 5, i = t & 31;
  float f = powf(10000.0f, -(float)i * (1.0f / 32.0f));
  float a = (float)pos * f;
  tc[t] = cosf(a);
  ts[t] = sinf(a);
}

// ---------------- fused QKV GEMM ----------------
// grid (32, 24): blockIdx.y>>3 selects Q/K/V, (blockIdx.y&7)*128 = n0.
// Q,K: bf16 out [M][1024]. V: bf16 out transposed [B][H][64][S] via LDS transpose.
// Counted-vmcnt split-barrier pipeline (T3/T4 minimum): loads span barriers.
__global__ __launch_bounds__(256) void qkv_kernel(
    const bf16* __restrict__ A,
    const bf16* __restrict__ Wq, const bf16* __restrict__ Wk, const bf16* __restrict__ Wv,
    const float* __restrict__ bq, const float* __restrict__ bk, const float* __restrict__ bv,
    unsigned short* __restrict__ qo, unsigned short* __restrict__ ko,
    unsigned short* __restrict__ vt) {
  __shared__ bf16 smem[16384];  // sA[2][4096] | sB[2][4096]; reused as ct[128][128]
  bf16* sAp = smem;
  bf16* sBp = smem + 8192;
  const int sel = blockIdx.y >> 3;
  const bf16* Bw = (sel == 0) ? Wq : (sel == 1) ? Wk : Wv;
  const float* bias = (sel == 0) ? bq : (sel == 1) ? bk : bv;
  const int tid = threadIdx.x;
  const int lane = tid & 63, wave = tid >> 6;
  const int wr = wave >> 1, wc = wave & 1;
  const int fr = lane & 15, fq = lane >> 4;
  const int m0 = blockIdx.x * 128, n0 = (blockIdx.y & 7) * 128;

  floatx4 acc[4][4] = {};
  const int sr = tid >> 2;
  const int sc8 = (tid & 3) * 8;

  auto stage = [&](int buf, int k0) {
#pragma unroll
    for (int call = 0; call < 2; ++call) {
      int row = call * 64 + sr;
      gload_lds16(A + (size_t)(m0 + row) * 1024 + k0 + sc8,
                  sAp + buf * 4096 + call * 2048 + wave * 512);
      gload_lds16(Bw + (size_t)(n0 + row) * 1024 + k0 + sc8,
                  sBp + buf * 4096 + call * 2048 + wave * 512);
    }
  };

  stage(0, 0);
  stage(1, 32);
  int cur = 0;
  for (int k0 = 0; k0 < 1024; k0 += 32) {
    if (k0 + 32 < 1024) wait_vm4(); else wait_vm0();
    __builtin_amdgcn_s_barrier();
    __builtin_amdgcn_sched_barrier(0);
    short8 af[4], bfr[4];
#pragma unroll
    for (int mi = 0; mi < 4; ++mi)
      af[mi] = *(const short8*)(sAp + cur * 4096 + (wr * 64 + mi * 16 + fr) * 32 + fq * 8);
#pragma unroll
    for (int ni = 0; ni < 4; ++ni)
      bfr[ni] = *(const short8*)(sBp + cur * 4096 + (wc * 64 + ni * 16 + fr) * 32 + fq * 8);
#pragma unroll
    for (int mi = 0; mi < 4; ++mi)
#pragma unroll
      for (int ni = 0; ni < 4; ++ni)
        acc[mi][ni] = __builtin_amdgcn_mfma_f32_16x16x32_bf16(af[mi], bfr[ni], acc[mi][ni], 0, 0, 0);
    __builtin_amdgcn_sched_barrier(0);
    __builtin_amdgcn_s_barrier();
    if (k0 + 64 < 1024) stage(cur, k0 + 64);
    cur ^= 1;
  }

  if (sel < 2) {
    unsigned short* dst = (sel == 0) ? qo : ko;
#pragma unroll
    for (int mi = 0; mi < 4; ++mi)
#pragma unroll
      for (int ni = 0; ni < 4; ++ni)
#pragma unroll
        for (int j = 0; j < 4; ++j) {
          int m = m0 + wr * 64 + mi * 16 + fq * 4 + j;
          int n = n0 + wc * 64 + ni * 16 + fr;
          dst[(size_t)m * 1024 + n] = bfbits(acc[mi][ni][j] + bias[n]);
        }
  } else {
    // V: transpose tile through LDS (XOR-swizzled), write coalesced 16B runs.
    __syncthreads();  // staging LDS fully consumed (loop drained at tail)
    char* ct = (char*)smem;  // [n=128][m=128] bf16, row 256B, byte ^= (n&15)<<4
#pragma unroll
    for (int mi = 0; mi < 4; ++mi)
#pragma unroll
      for (int ni = 0; ni < 4; ++ni) {
        int nl = wc * 64 + ni * 16 + fr;
        float bi = bias[n0 + nl];
#pragma unroll
        for (int j = 0; j < 4; j += 2) {
          int ml = wr * 64 + mi * 16 + fq * 4 + j;
          unsigned int u = (unsigned int)bfbits(acc[mi][ni][j] + bi) |
                           ((unsigned int)bfbits(acc[mi][ni][j + 1] + bi) << 16);
          *(unsigned int*)(ct + nl * 256 + ((ml * 2) ^ ((nl & 15) << 4))) = u;
        }
      }
    __syncthreads();
    int nl = tid >> 1;
    int mb = (tid & 1) * 64;
    int hh = (n0 + nl) >> 6, dd = (n0 + nl) & 63;
    int b = m0 >> 11, s0 = m0 & 2047;
    unsigned short* orow = vt + (((size_t)b * 16 + hh) * 64 + dd) * 2048 + s0 + mb;
#pragma unroll
    for (int c = 0; c < 8; ++c) {
      short8 v8 = *(const short8*)(ct + nl * 256 + (((mb + c * 8) * 2) ^ ((nl & 15) << 4)));
      *(short8*)(orow + c * 8) = v8;
    }
  }
}

// ---------------- Wo GEMM: f32 out ----------------
__global__ __launch_bounds__(256) void gemm_bt_kernel(
    const bf16* __restrict__ A, const bf16* __restrict__ Bw,
    const float* __restrict__ bias, float* __restrict__ Cf) {
  __shared__ bf16 sA[2][128 * 32];
  __shared__ bf16 sB[2][128 * 32];
  const int tid = threadIdx.x;
  const int lane = tid & 63, wave = tid >> 6;
  const int wr = wave >> 1, wc = wave & 1;
  const int fr = lane & 15, fq = lane >> 4;
  const int m0 = blockIdx.x * 128, n0 = blockIdx.y * 128;

  floatx4 acc[4][4] = {};
  const int sr = tid >> 2;
  const int sc8 = (tid & 3) * 8;

  auto stage = [&](int buf, int k0) {
#pragma unroll
    for (int call = 0; call < 2; ++call) {
      int row = call * 64 + sr;
      gload_lds16(A + (size_t)(m0 + row) * 1024 + k0 + sc8, &sA[buf][call * 2048 + wave * 512]);
      gload_lds16(Bw + (size_t)(n0 + row) * 1024 + k0 + sc8, &sB[buf][call * 2048 + wave * 512]);
    }
  };

  stage(0, 0);
  stage(1, 32);
  int cur = 0;
  for (int k0 = 0; k0 < 1024; k0 += 32) {
    if (k0 + 32 < 1024) wait_vm4(); else wait_vm0();
    __builtin_amdgcn_s_barrier();
    __builtin_amdgcn_sched_barrier(0);
    short8 af[4], bfr[4];
#pragma unroll
    for (int mi = 0; mi < 4; ++mi)
      af[mi] = *(const short8*)(&sA[cur][(wr * 64 + mi * 16 + fr) * 32 + fq * 8]);
#pragma unroll
    for (int ni = 0; ni < 4; ++ni)
      bfr[ni] = *(const short8*)(&sB[cur][(wc * 64 + ni * 16 + fr) * 32 + fq * 8]);
#pragma unroll
    for (int mi = 0; mi < 4; ++mi)
#pragma unroll
      for (int ni = 0; ni < 4; ++ni)
        acc[mi][ni] = __builtin_amdgcn_mfma_f32_16x16x32_bf16(af[mi], bfr[ni], acc[mi][ni], 0, 0, 0);
    __builtin_amdgcn_sched_barrier(0);
    __builtin_amdgcn_s_barrier();
    if (k0 + 64 < 1024) stage(cur, k0 + 64);
    cur ^= 1;
  }

#pragma unroll
  for (int mi = 0; mi < 4; ++mi)
#pragma unroll
    for (int ni = 0; ni < 4; ++ni)
#pragma unroll
      for (int j = 0; j < 4; ++j) {
        int m = m0 + wr * 64 + mi * 16 + fq * 4 + j;
        int n = n0 + wc * 64 + ni * 16 + fr;
        Cf[(size_t)m * 1024 + n] = acc[mi][ni][j] + bias[n];
      }
}

// ---------------- RoPE + l2norm: bf16 [B,S,H,64] -> bf16 [B,H,S,64] ----------------
__global__ __launch_bounds__(256) void rope_norm_kernel(
    const unsigned short* __restrict__ qf, const unsigned short* __restrict__ kf,
    const float* __restrict__ tc, const float* __restrict__ ts,
    unsigned short* __restrict__ qb, unsigned short* __restrict__ kb) {
  int gr = blockIdx.x * 8 + (threadIdx.x >> 5);  // row id over 2*65536
  int j = threadIdx.x & 31;                      // pair index within head dim
  const unsigned short* src;
  unsigned short* dst;
  int rr;
  if (gr < Mn * Hn) { src = qf; dst = qb; rr = gr; }
  else { src = kf; dst = kb; rr = gr - Mn * Hn; }
  int h = rr & 15, bs = rr >> 4;
  int s = bs & 2047, b = bs >> 11;
  ushort2 xr = *(const ushort2*)(src + (size_t)bs * 1024 + h * 64 + 2 * j);
  float x0 = bf2f(xr.x), x1 = bf2f(xr.y);
  float c = tc[s * 32 + j], sn = ts[s * 32 + j];
  float y0 = x0 * c - x1 * sn;
  float y1 = x1 * c + x0 * sn;
  float ssq = y0 * y0 + y1 * y1;
#pragma unroll
  for (int msk = 1; msk < 32; msk <<= 1) ssq += __shfl_xor(ssq, msk);
  float inv = rsqrtf(ssq + 1e-6f);
  size_t o = (((size_t)b * 16 + h) * 2048 + s) * 64 + 2 * j;
  ushort2 pk;
  pk.x = bfbits(y0 * inv);
  pk.y = bfbits(y1 * inv);
  *(ushort2*)(dst + o) = pk;
}

// ---------------- causal flash attention, split-letter paired q-tiles ----------------
// grid (32, 32): waves 0,1 own 32-row q-tile at q0A=bid.x*32; waves 2,3 own
// q0B=(63-bid.x)*32. KVBLK=64, depth-2 prefetch with counted vmcnt + raw
// barriers (no full drain). LDS 40KB -> 4 blocks/CU.
__global__ __launch_bounds__(256, 4) void attn_kernel(
    const bf16* __restrict__ qb, const bf16* __restrict__ kb, const bf16* __restrict__ vt,
    const float* __restrict__ ls, unsigned short* __restrict__ out) {
  __shared__ bf16 sK[2][64 * 64];   // [kv][d], 128B rows, swz (row&7)<<4
  __shared__ bf16 sV[2][64 * 64];   // [d][kv], 128B rows, swz (row&7)<<4
  __shared__ char p_lds[4][2048];   // per wave: 16x64 bf16, swz (prow&7)<<4
  const int q0A = blockIdx.x * 32, q0B = (63 - (int)blockIdx.x) * 32;
  const int bh = blockIdx.y;
  const int tid = threadIdx.x;
  const int lane = tid & 63, wave = tid >> 6;
  const int fr = lane & 15, fq = lane >> 4;
  const int myq0 = (wave >= 2) ? q0B : q0A;
  const int base = myq0 + (wave & 1) * 16;   // first q-row of this wave
  float scl2 = __expf(ls[0]) * 0.125f * 1.44269504f;

  const size_t qrow = (size_t)bh * 2048 + base + fr;
  short8 qf0 = *(const short8*)(qb + qrow * 64 + fq * 8);
  short8 qf1 = *(const short8*)(qb + qrow * 64 + 32 + fq * 8);
  // detach qf/scl2 from their defining loads so the compiler doesn't emit
  // conservative in-loop vmcnt waits for them (wait happens here, once).
  asm volatile("" : "+v"(qf0), "+v"(qf1), "+v"(scl2));
  __builtin_amdgcn_sched_barrier(0);

  const bf16* kgb = kb + (size_t)bh * 2048 * 64;
  const bf16* vgb = vt + (size_t)bh * 64 * 2048;

  auto stage = [&](int buf, int t0) {
#pragma unroll
    for (int call = 0; call < 2; ++call) {
      int row = call * 32 + (tid >> 3);
      int sb = ((tid & 7) * 16) ^ ((row & 7) << 4);
      gload_lds16(kgb + (size_t)(t0 + row) * 64 + sb / 2,
                  &sK[buf][call * 2048 + wave * 512]);
    }
#pragma unroll
    for (int call = 0; call < 2; ++call) {
      int row = call * 32 + (tid >> 3);
      int sb = ((tid & 7) * 16) ^ ((row & 7) << 4);
      gload_lds16(vgb + (size_t)row * 2048 + t0 + sb / 2,
                  &sV[buf][call * 2048 + wave * 512]);
    }
  };

  floatx4 oacc[4] = {};
  float mb2[4], lrun[4];
#pragma unroll
  for (int r = 0; r < 4; ++r) { mb2[r] = -INFINITY; lrun[r] = 0.f; }
  const int rowq = base + fq * 4;            // + r
  const int sw = (fr & 7) << 4;
  char* pw = p_lds[wave];
  short8 onesf;
#pragma unroll
  for (int i = 0; i < 8; ++i) onesf[i] = 0x3F80;  // bf16 1.0

  const int tEnd = q0B + 32;
  stage(0, 0);
  stage(1, 64);
  int cur = 0;
  for (int t0 = 0; t0 < tEnd; t0 += 64) {
    if (t0 + 64 < tEnd) wait_vm4(); else wait_vm0();
    __builtin_amdgcn_s_barrier();
    __builtin_amdgcn_sched_barrier(0);
    if (t0 < myq0 + 32) {  // this wave's letter still active
      const char* sKc = (const char*)sK[cur];
      const char* sVc = (const char*)sV[cur];
      floatx4 sacc[4] = {};
      __builtin_amdgcn_s_setprio(1);
#pragma unroll
      for (int c = 0; c < 4; ++c) {
        int rb = (c * 16 + fr) * 128;
        short8 kf0 = *(const short8*)(sKc + rb + ((fq * 16) ^ sw));
        short8 kf1 = *(const short8*)(sKc + rb + ((64 + fq * 16) ^ sw));
        sacc[c] = __builtin_amdgcn_mfma_f32_16x16x32_bf16(qf0, kf0, sacc[c], 0, 0, 0);
        sacc[c] = __builtin_amdgcn_mfma_f32_16x16x32_bf16(qf1, kf1, sacc[c], 0, 0, 0);
      }
      __builtin_amdgcn_s_setprio(0);
      if (t0 + 63 > rowq) {  // causal mask needed on this substep
#pragma unroll
        for (int c = 0; c < 4; ++c)
#pragma unroll
          for (int r = 0; r < 4; ++r)
            if ((t0 + c * 16 + fr) > (rowq + r)) sacc[c][r] = -1e30f;
      }
      float pl[4];
#pragma unroll
      for (int r = 0; r < 4; ++r)
        pl[r] = fmaxf(fmaxf(sacc[0][r], sacc[1][r]), fmaxf(sacc[2][r], sacc[3][r]));
      float cmax = -INFINITY;
#pragma unroll
      for (int r = 0; r < 4; ++r) cmax = fmaxf(cmax, pl[r] * scl2 - mb2[r]);
      if (!__all(cmax <= 11.5f)) {  // slow path: full row-max + rescale
#pragma unroll
        for (int r = 0; r < 4; ++r) {
          float pm = pl[r];
#pragma unroll
          for (int msk = 1; msk < 16; msk <<= 1) pm = fmaxf(pm, __shfl_xor(pm, msk));
          float mnew = fmaxf(mb2[r], pm * scl2);
          float rs = EXP2(mb2[r] - mnew);
          mb2[r] = mnew;
          lrun[r] *= rs;
#pragma unroll
          for (int d = 0; d < 4; ++d) oacc[d][r] *= rs;
        }
      }
#pragma unroll
      for (int c = 0; c < 4; ++c)
#pragma unroll
        for (int r = 0; r < 4; ++r) {
          union { float f; unsigned int u; } pu;
          pu.f = EXP2(sacc[c][r] * scl2 - mb2[r]);
          int prow = fq * 4 + r;
          *(unsigned short*)(pw + prow * 128 + ((c * 32 + 2 * fr) ^ ((prow & 7) << 4))) =
              (unsigned short)(pu.u >> 16);
        }
      short8 pf0 = *(const short8*)(pw + fr * 128 + ((fq * 16) ^ sw));
      short8 pf1 = *(const short8*)(pw + fr * 128 + ((64 + fq * 16) ^ sw));
      __builtin_amdgcn_s_setprio(1);
      floatx4 tsum = {};
      tsum = __builtin_amdgcn_mfma_f32_16x16x32_bf16(pf0, onesf, tsum, 0, 0, 0);
      tsum = __builtin_amdgcn_mfma_f32_16x16x32_bf16(pf1, onesf, tsum, 0, 0, 0);
#pragma unroll
      for (int d = 0; d < 4; ++d) {
        int rb = (d * 16 + fr) * 128;
        short8 vf0 = *(const short8*)(sVc + rb + ((fq * 16) ^ sw));
        short8 vf1 = *(const short8*)(sVc + rb + ((64 + fq * 16) ^ sw));
        oacc[d] = __builtin_amdgcn_mfma_f32_16x16x32_bf16(pf0, vf0, oacc[d], 0, 0, 0);
        oacc[d] = __builtin_amdgcn_mfma_f32_16x16x32_bf16(pf1, vf1, oacc[d], 0, 0, 0);
      }
      __builtin_amdgcn_s_setprio(0);
#pragma unroll
      for (int r = 0; r < 4; ++r) lrun[r] += tsum[r];
    }
    __builtin_amdgcn_sched_barrier(0);
    __builtin_amdgcn_s_barrier();
    if (t0 + 128 < tEnd) stage(cur, t0 + 128);
    cur ^= 1;
  }
  const int b = bh >> 4, h = bh & 15;
#pragma unroll
  for (int r = 0; r < 4; ++r) {
    float il = 1.0f / lrun[r];
#pragma unroll
    for (int d = 0; d < 4; ++d) {
      size_t o = ((size_t)b * 2048 + rowq + r) * 1024 + h * 64 + d * 16 + fr;
      out[o] = bfbits(oacc[d][r] * il);
    }
  }
}

extern "C" void kernel_launch(void* const* d_in, const int* in_sizes, int n_in,
                              void* d_out, int out_size, void* d_ws, size_t ws_size,
                              hipStream_t stream) {
  (void)in_sizes; (void)n_in; (void)out_size; (void)ws_size;
  const float* x  = (const float*)d_in[0];
  const float* Wq = (const float*)d_in[1];
  const float* bq = (const float*)d_in[2];
  const float* Wk = (const float*)d_in[3];
  const float* bk = (const float*)d_in[4];
  const float* Wv = (const float*)d_in[5];
  const float* bv = (const float*)d_in[6];
  const float* Wo = (const float*)d_in[7];
  const float* bo = (const float*)d_in[8];
  const float* lsc = (const float*)d_in[9];
  // d_in[10] = mask: fixed causal triu(k=1), implemented analytically.

  uint8_t* w = (uint8_t*)d_ws;
  const size_t MB = 1ull << 20;
  bf16* xb   = (bf16*)(w + 0);          // 8 MB
  bf16* wqb  = (bf16*)(w + 8 * MB);     // 2 MB each
  bf16* wkb  = (bf16*)(w + 10 * MB);
  bf16* wvb  = (bf16*)(w + 12 * MB);
  bf16* wob  = (bf16*)(w + 14 * MB);
  bf16* qraw = (bf16*)(w + 16 * MB);    // 8 MB  bf16 [B,S,DIM]
  bf16* kraw = (bf16*)(w + 24 * MB);    // 8 MB
  bf16* qbn  = (bf16*)(w + 32 * MB);    // 8 MB  [B,H,S,64]
  bf16* kbn  = (bf16*)(w + 40 * MB);    // 8 MB
  bf16* vtb  = (bf16*)(w + 48 * MB);    // 8 MB  [B,H,64,S]
  bf16* atb  = (bf16*)(w + 56 * MB);    // 8 MB  [B,S,DIM]
  float* tc  = (float*)(w + 64 * MB);   // 256 KB
  float* ts  = (float*)(w + 64 * MB + 256 * 1024);

  cvt_kernel<<<4096, 256, 0, stream>>>(x, (unsigned short*)xb, Mn * DIMn / 4);
  cvt4_kernel<<<dim3(1024, 4), 256, 0, stream>>>(
      Wq, Wk, Wv, Wo, (unsigned short*)wqb, (unsigned short*)wkb,
      (unsigned short*)wvb, (unsigned short*)wob);
  rope_tab_kernel<<<256, 256, 0, stream>>>(tc, ts);

  qkv_kernel<<<dim3(32, 24), 256, 0, stream>>>(
      xb, wqb, wkb, wvb, bq, bk, bv,
      (unsigned short*)qraw, (unsigned short*)kraw, (unsigned short*)vtb);

  rope_norm_kernel<<<Mn * Hn * 2 / 8, 256, 0, stream>>>(
      (const unsigned short*)qraw, (const unsigned short*)kraw, tc, ts,
      (unsigned short*)qbn, (unsigned short*)kbn);

  attn_kernel<<<dim3(32, Bn * Hn), 256, 0, stream>>>(qbn, kbn, vtb, lsc,
                                                     (unsigned short*)atb);

  gemm_bt_kernel<<<dim3(Mn / 128, DIMn / 128), 256, 0, stream>>>(atb, wob, bo, (float*)d_out);
}